// Round 10
// baseline (288.917 us; speedup 1.0000x reference)
//
#include <hip/hip_runtime.h>
#include <hip/hip_bf16.h>
#include <cstdint>
#include <cstddef>

typedef unsigned short u16;
typedef __attribute__((ext_vector_type(4))) unsigned short u16x4;
typedef __attribute__((ext_vector_type(8))) unsigned short u16x8;
typedef __attribute__((ext_vector_type(8))) __bf16 bf16x8;
typedef __attribute__((ext_vector_type(4))) float f32x4;

#define MFMA16(a, b, c) __builtin_amdgcn_mfma_f32_16x16x32_bf16((a), (b), (c), 0, 0, 0)

__device__ __forceinline__ u16 f2bf(float f) {
  uint32_t u = __builtin_bit_cast(uint32_t, f);
  u += 0x7FFFu + ((u >> 16) & 1u);
  return (u16)(u >> 16);
}
__device__ __forceinline__ float bf2f(u16 h) {
  return __builtin_bit_cast(float, (uint32_t)h << 16);
}

typedef const __attribute__((address_space(1))) void gv_t;
typedef __attribute__((address_space(3))) void lv_t;
__device__ __forceinline__ void gload16(const void* g, void* l) {
  __builtin_amdgcn_global_load_lds((gv_t*)g, (lv_t*)l, 16, 0, 0);
}

// ---------------- f32 -> bf16 convert (vectorized) ----------------
__global__ void cvt_f32_to_bf16(const float* __restrict__ in, u16* __restrict__ out, int n4) {
  int i = blockIdx.x * 256 + threadIdx.x;
  if (i >= n4) return;
  float4 v = ((const float4*)in)[i];
  u16x4 o;
  o[0] = f2bf(v.x); o[1] = f2bf(v.y); o[2] = f2bf(v.z); o[3] = f2bf(v.w);
  ((u16x4*)out)[i] = o;
}

// ------------- transpose + convert x4: W[2048][2048] f32 -> Wt bf16 [N][K], z picks W -------------
__global__ void transpose_cvt4(const float* __restrict__ w0, const float* __restrict__ w1,
                               const float* __restrict__ w2, const float* __restrict__ w3,
                               u16* __restrict__ outbase) {
  __shared__ float tile[32][33];
  const int z = blockIdx.z;
  const float* in = (z == 0) ? w0 : (z == 1) ? w1 : (z == 2) ? w2 : w3;
  u16* out = outbase + (size_t)z * 4194304;  // 2048*2048 each
  const int bx = blockIdx.x, by = blockIdx.y;
  const int tx = threadIdx.x, ty = threadIdx.y;
#pragma unroll
  for (int i = 0; i < 32; i += 8)
    tile[ty + i][tx] = in[(size_t)(by * 32 + ty + i) * 2048 + bx * 32 + tx];
  __syncthreads();
#pragma unroll
  for (int i = 0; i < 32; i += 8)
    out[(size_t)(bx * 32 + ty + i) * 2048 + by * 32 + tx] = f2bf(tile[tx][ty + i]);
}

// ------------- per-head transpose of V: bf16 [B*S][H*dk] -> VT [B,H,dk,S] -------------
__global__ void vtrans(const u16* __restrict__ in, u16* __restrict__ out) {
  __shared__ u16 tile[32][34];
  const int bx = blockIdx.x, by = blockIdx.y;
  const int tx = threadIdx.x, ty = threadIdx.y;
#pragma unroll
  for (int i = 0; i < 32; i += 8)
    tile[ty + i][tx] = in[(size_t)(by * 32 + ty + i) * 2048 + bx * 32 + tx];
  __syncthreads();
#pragma unroll
  for (int i = 0; i < 32; i += 8) {
    const int c = bx * 32 + ty + i;      // 0..2047 = h*128 + d
    const int token = by * 32 + tx;      // 0..4095 = b*2048 + s
    out[(((size_t)(token >> 11) * 16 + (c >> 7)) * 128 + (c & 127)) * 2048 + (token & 2047)] =
        tile[tx][ty + i];
  }
}

// ============ merged-phase GEMM: C[M,*] = A[M,2048] * Bt[*,2048]^T ============
// BM=256, BN=128, BK=64, 512 threads (8 waves: 4M x 2N, per-wave 64x64).
// 3-deep LDS pipeline, counted vmcnt(6), ONE barrier per K-tile. T2 swizzle both-sides.
// L2 raster: each XCD owns nbn/8 B-columns x ALL bm rows -> B-panels L2-resident per XCD.
// MODE 1: f32 C [M][2048].  MODE 2: bf16 QKV split + FUSED RoPE (no-scratch __sinf/__cosf).
template <int MODE>
__global__ __launch_bounds__(512, 1) void gemm8(const u16* __restrict__ A,
                                                const u16* __restrict__ Bt,
                                                void* __restrict__ Cv,
                                                const int* __restrict__ pos, int nbn) {
  constexpr int K = 2048;
  __shared__ __align__(16) u16 lds[73728];  // 3 x (A 32KB + B 16KB) = 144KB
  const int tid = threadIdx.x, lane = tid & 63;
  const int lo16 = lane & 15, hi = lane >> 4;
  const int wid = tid >> 6;
  const int wr = wid >> 1, wc = wid & 1;

  // XCD-owned B-column raster: xcd owns cpx consecutive bn columns, sweeps all bm.
  const int xcd = (int)blockIdx.x & 7;
  const int idx = (int)blockIdx.x >> 3;   // 0..grid/8-1
  const int cpx = nbn >> 3;               // B-cols per XCD (48->6, 16->2)
  const int bn = (xcd * cpx + idx % cpx) * 128;
  const int bm = (idx / cpx) * 256;

  // staging: round = 64 rows x 64 cols, thread -> (row=tid>>3, 16B slot=tid&7)
  const int srow = tid >> 3;
  const int scol = ((tid & 7) ^ (srow & 7)) * 8;  // pre-swizzled source col (elements)
  const u16* Arow = A + (size_t)(bm + srow) * K + scol;
  const u16* Brow = Bt + (size_t)(bn + srow) * K + scol;
  char* dstbase = (char*)lds + tid * 16;

#define STG_A(qb_, t_, r_) \
  gload16(Arow + (size_t)(r_) * 64 * K + (t_) * 64, dstbase + (qb_) * 49152 + (r_) * 8192)
#define STG_B(qb_, t_, r_) \
  gload16(Brow + (size_t)(r_) * 64 * K + (t_) * 64, dstbase + (qb_) * 49152 + 32768 + (r_) * 8192)

  f32x4 acc[4][4];
  const f32x4 z4 = {0.f, 0.f, 0.f, 0.f};
#pragma unroll
  for (int m = 0; m < 4; ++m)
#pragma unroll
    for (int n = 0; n < 4; ++n) acc[m][n] = z4;

  // ds_read address components (bytes)
  const int xork = lo16 & 7;
  const int aRow = (wr * 64 + lo16) * 128;          // + m*2048
  const int bRow = 32768 + (wc * 64 + lo16) * 128;  // + n*2048
  const int x0 = ((hi ^ xork)) << 4;                // kk=0 slot
  const int x1 = (((4 + hi) ^ xork)) << 4;          // kk=1 slot

  // prologue: stage tiles 0 and 1
  STG_A(0, 0, 0); STG_A(0, 0, 1); STG_A(0, 0, 2); STG_A(0, 0, 3);
  STG_B(0, 0, 0); STG_B(0, 0, 1);
  STG_A(1, 1, 0); STG_A(1, 1, 1); STG_A(1, 1, 2); STG_A(1, 1, 3);
  STG_B(1, 1, 0); STG_B(1, 1, 1);

  int q = 0;
  for (int t = 0; t < 32; ++t) {
    if (t < 31) {
      asm volatile("s_waitcnt vmcnt(6)" ::: "memory");  // own tile-t loads landed
    } else {
      asm volatile("s_waitcnt vmcnt(0)" ::: "memory");
    }
    __builtin_amdgcn_s_barrier();          // all waves' tile-t loads landed
    __builtin_amdgcn_sched_barrier(0);     // nothing hoists above the barrier
    const char* Aq = (const char*)lds + q * 49152;
    const int q2 = (q == 0) ? 2 : q - 1;   // buffer for tile t+2

    bf16x8 a0[4], b0[4], a1[4], b1[4];
#pragma unroll
    for (int m = 0; m < 4; ++m) a0[m] = *(const bf16x8*)(Aq + aRow + m * 2048 + x0);
#pragma unroll
    for (int n = 0; n < 4; ++n) b0[n] = *(const bf16x8*)(Aq + bRow + n * 2048 + x0);
#pragma unroll
    for (int m = 0; m < 4; ++m) a1[m] = *(const bf16x8*)(Aq + aRow + m * 2048 + x1);
#pragma unroll
    for (int n = 0; n < 4; ++n) b1[n] = *(const bf16x8*)(Aq + bRow + n * 2048 + x1);

    if (t < 30) {
      STG_A(q2, t + 2, 0); STG_A(q2, t + 2, 1); STG_A(q2, t + 2, 2); STG_A(q2, t + 2, 3);
      STG_B(q2, t + 2, 0); STG_B(q2, t + 2, 1);
    }

    __builtin_amdgcn_s_setprio(1);
#pragma unroll
    for (int m = 0; m < 4; ++m)
#pragma unroll
      for (int n = 0; n < 4; ++n) acc[m][n] = MFMA16(a0[m], b0[n], acc[m][n]);
#pragma unroll
    for (int m = 0; m < 4; ++m)
#pragma unroll
      for (int n = 0; n < 4; ++n) acc[m][n] = MFMA16(a1[m], b1[n], acc[m][n]);
    __builtin_amdgcn_s_setprio(0);
    q = (q == 2) ? 0 : q + 1;
  }
#undef STG_A
#undef STG_B

  // ---- epilogue ----
  if constexpr (MODE == 2) {
    const int sect = bn >> 11;  // 0=Q, 1=K, 2=V (buffers 16MB apart = 8388608 u16)
    u16* Cq = (u16*)Cv + (size_t)sect * 8388608;
    const int cb = (bn & 2047) + wc * 64;
    if (sect < 2) {
      // fused RoPE: lane pairs (lo16^1) hold the (even,odd) column pair.
      // __sinf/__cosf (value-returning) -- NO sincosf (scratch spill, round-8 lesson).
      const float qsc = (sect == 0) ? 0.08838834764831845f : 1.0f;
      float freq[4];
#pragma unroll
      for (int n = 0; n < 4; ++n) {
        const int c = cb + n * 16 + lo16;
        freq[n] = exp2f((float)((c & 127) >> 1) * -0.2076205059304601f);
      }
      const float sg = (lo16 & 1) ? 1.f : -1.f;  // cb, n*16 are even
#pragma unroll
      for (int m = 0; m < 4; ++m) {
        const int row = bm + wr * 64 + m * 16 + hi * 4;
#pragma unroll
        for (int r = 0; r < 4; ++r) {
          const float p = (float)pos[row + r];
#pragma unroll
          for (int n = 0; n < 4; ++n) {
            const float ang = p * freq[n];
            const float sn = __sinf(ang);
            const float cs = __cosf(ang);
            const float v = acc[m][n][r];
            const float pv = __shfl_xor(v, 1);
            Cq[(size_t)(row + r) * 2048 + cb + n * 16 + lo16] =
                f2bf((v * cs + sg * pv * sn) * qsc);
          }
        }
      }
    } else {
#pragma unroll
      for (int m = 0; m < 4; ++m)
#pragma unroll
        for (int n = 0; n < 4; ++n)
#pragma unroll
          for (int r = 0; r < 4; ++r)
            Cq[(size_t)(bm + wr * 64 + m * 16 + hi * 4 + r) * 2048 + cb + n * 16 + lo16] =
                f2bf(acc[m][n][r]);
    }
  } else {
    float* C = (float*)Cv;
    const int cb = bn + wc * 64;
#pragma unroll
    for (int m = 0; m < 4; ++m)
#pragma unroll
      for (int n = 0; n < 4; ++n)
#pragma unroll
        for (int r = 0; r < 4; ++r)
          C[(size_t)(bm + wr * 64 + m * 16 + hi * 4 + r) * 2048 + cb + n * 16 + lo16] =
              acc[m][n][r];
  }
}

// ------------- causal flash attention v5: QTILE=64, KVBLK=64, SINGLE-buffered, 4 blocks/CU -------------
// One q-tile per block (grid 1024). LDS 40KB exactly -> 4 blocks/CU; the exposed staging
// stall per step is hidden by 4-way cross-block TLP. Heads pinned to XCDs (K/V 4MB = L2);
// qt descending within XCD so heavy blocks dispatch first; dynamic refill balances.
__global__ __launch_bounds__(256, 4) void flash_attn5(const u16* __restrict__ Qb,
                                                      const u16* __restrict__ Kb,
                                                      const u16* __restrict__ VT,
                                                      u16* __restrict__ Ob) {
  constexpr int S = 2048, HD = 2048;
  const int g = (int)blockIdx.x;
  const int xcd = g & 7, slot = g >> 3;      // 128 slots per XCD
  const int bh = xcd * 4 + (slot & 3);       // 4 heads per XCD
  const int qt = 31 - (slot >> 2);           // heavy first
  const int b = bh >> 4, h = bh & 15;
  const int tid = threadIdx.x, lane = tid & 63, wid = tid >> 6;
  const int q0 = qt * 64;

  __shared__ u16 Ks[64 * 128];   // [kv][d] swizzled (16KB)
  __shared__ u16 Vs[128 * 64];   // [d][kv] swizzled (16KB)
  __shared__ u16 Ps[4][16 * 64]; // per-wave P [q][kv], swizzled (8KB)

  const size_t base = (size_t)b * S * HD + (size_t)h * 128;
  const u16* Qp = Qb + base;
  const u16* Kp = Kb + base;
  const u16* VTp = VT + (size_t)bh * 128 * S;
  u16* Op = Ob + base;

  const f32x4 z4 = {0.f, 0.f, 0.f, 0.f};
  const int kKv = (lane >> 4);
  const int kC16 = (lane & 15);
  const int vD = (lane >> 3);
  const int vC16 = (lane & 7);

  // Q fragments (A operand): row = lane&15, k-chunk = (lane>>4)*8
  bf16x8 qf[4];
  {
    const int qr = q0 + wid * 16 + (lane & 15);
    const int kc = (lane >> 4) * 8;
#pragma unroll
    for (int kb = 0; kb < 4; ++kb)
      qf[kb] = *(const bf16x8*)(Qp + (size_t)qr * HD + kb * 32 + kc);
  }

  f32x4 accO[8];
#pragma unroll
  for (int d = 0; d < 8; ++d) accO[d] = z4;
  float m_r[4] = {-INFINITY, -INFINITY, -INFINITY, -INFINITY};
  float l_r[4] = {0.f, 0.f, 0.f, 0.f};

  for (int t = 0; t <= qt; ++t) {
    const int kv0 = t * 64;
    __syncthreads();  // prior step's LDS reads done

    // stage K tile + V^T tile (swizzle via pre-swizzled global source)
#pragma unroll
    for (int c = 0; c < 4; ++c) {
      const int ch = wid * 4 + c;
      {
        const int kv = ch * 4 + kKv;
        const int c16 = kC16 ^ (kv & 7);
        gload16(Kp + (size_t)(kv0 + kv) * HD + c16 * 8, (char*)Ks + ch * 1024);
      }
      {
        const int d = ch * 8 + vD;
        const int c16 = vC16 ^ (d & 7);
        gload16(VTp + (size_t)d * S + kv0 + c16 * 8, (char*)Vs + ch * 1024);
      }
    }
    __syncthreads();  // staging visible (drains vmcnt)

    f32x4 accS[4];
#pragma unroll
    for (int nb = 0; nb < 4; ++nb) accS[nb] = z4;

    // ---- S = Q K^T ----
    __builtin_amdgcn_s_setprio(1);
#pragma unroll
    for (int nb = 0; nb < 4; ++nb) {
      const int kv = nb * 16 + (lane & 15);
#pragma unroll
      for (int kb = 0; kb < 4; ++kb) {
        const int c16 = (kb * 4 + (lane >> 4)) ^ (kv & 7);
        bf16x8 kf = *(const bf16x8*)((char*)Ks + kv * 256 + c16 * 16);
        accS[nb] = MFMA16(qf[kb], kf, accS[nb]);
      }
    }
    __builtin_amdgcn_s_setprio(0);

    // ---- causal mask (diagonal step only) ----
    if (t == qt) {
#pragma unroll
      for (int nb = 0; nb < 4; ++nb) {
        const int kv = kv0 + nb * 16 + (lane & 15);
        const int qrow = q0 + wid * 16 + (lane >> 4) * 4;
#pragma unroll
        for (int j = 0; j < 4; ++j)
          if (kv > qrow + j) accS[nb][j] = -INFINITY;
      }
    }

    // ---- online softmax (row = (lane>>4)*4+j) + P write ----
    u16* Pw = &Ps[wid][0];
#pragma unroll
    for (int j = 0; j < 4; ++j) {
      float mx = fmaxf(fmaxf(accS[0][j], accS[1][j]), fmaxf(accS[2][j], accS[3][j]));
#pragma unroll
      for (int off = 1; off < 16; off <<= 1) mx = fmaxf(mx, __shfl_xor(mx, off));
      const float mn = fmaxf(m_r[j], mx);
      const float sc = __expf(m_r[j] - mn);
      m_r[j] = mn;
      float s = 0.f;
#pragma unroll
      for (int nb = 0; nb < 4; ++nb) {
        const float p = __expf(accS[nb][j] - mn);
        accS[nb][j] = p;
        s += p;
      }
#pragma unroll
      for (int off = 1; off < 16; off <<= 1) s += __shfl_xor(s, off);
      l_r[j] = l_r[j] * sc + s;
#pragma unroll
      for (int db = 0; db < 8; ++db) accO[db][j] *= sc;
      const int ql = (lane >> 4) * 4 + j;
#pragma unroll
      for (int nb = 0; nb < 4; ++nb) {
        const int col = nb * 16 + (lane & 15);
        const int byteoff = ql * 128 + ((((col >> 3) ^ (ql & 7))) << 4) + (col & 7) * 2;
        *(u16*)((char*)Pw + byteoff) = f2bf(accS[nb][j]);
      }
    }

    // ---- O += P V ----
#pragma unroll
    for (int kb2 = 0; kb2 < 2; ++kb2) {
      const int ql = lane & 15;
      const int c16a = (kb2 * 4 + (lane >> 4)) ^ (ql & 7);
      bf16x8 pa = *(const bf16x8*)((char*)Pw + ql * 128 + c16a * 16);
      __builtin_amdgcn_s_setprio(1);
#pragma unroll
      for (int db = 0; db < 8; ++db) {
        const int d = db * 16 + (lane & 15);
        const int c16 = (kb2 * 4 + (lane >> 4)) ^ (d & 7);
        bf16x8 vf = *(const bf16x8*)((char*)Vs + d * 128 + c16 * 16);
        accO[db] = MFMA16(pa, vf, accO[db]);
      }
      __builtin_amdgcn_s_setprio(0);
    }
  }

  // ---- epilogue: normalize, store bf16 ----
  float inv[4];
#pragma unroll
  for (int j = 0; j < 4; ++j) inv[j] = 1.f / l_r[j];
#pragma unroll
  for (int db = 0; db < 8; ++db)
#pragma unroll
    for (int j = 0; j < 4; ++j) {
      const int row = q0 + wid * 16 + (lane >> 4) * 4 + j;
      Op[(size_t)row * HD + db * 16 + (lane & 15)] = f2bf(accO[db][j] * inv[j]);
    }
}

extern "C" void kernel_launch(void* const* d_in, const int* in_sizes, int n_in,
                              void* d_out, int out_size, void* d_ws, size_t ws_size,
                              hipStream_t stream) {
  const float* x  = (const float*)d_in[0];
  const int*   tp = (const int*)d_in[1];
  const float* WQ = (const float*)d_in[2];
  const float* WK = (const float*)d_in[3];
  const float* WV = (const float*)d_in[4];
  const float* WO = (const float*)d_in[5];

  const size_t MB = 1024 * 1024;
  if (ws_size < 112 * MB) return;
  char* ws = (char*)d_ws;
  u16* xb  = (u16*)(ws + 0 * MB);
  u16* wqt = (u16*)(ws + 16 * MB);   // wqt/wkt/wvt/wot contiguous, 8MB each
  u16* wot = (u16*)(ws + 40 * MB);
  u16* Qb  = (u16*)(ws + 48 * MB);   // Qb/Kb/Vb contiguous, 16MB apart
  u16* Kb  = (u16*)(ws + 64 * MB);
  u16* Vb  = (u16*)(ws + 80 * MB);
  u16* Obf = (u16*)(ws + 96 * MB);
  u16* VTb = xb;  // V^T [B,H,dk,S] (xb dead after projections)

  cvt_f32_to_bf16<<<8192, 256, 0, stream>>>(x, xb, 2097152);
  {
    dim3 g(64, 64, 4), blk(32, 8);
    transpose_cvt4<<<g, blk, 0, stream>>>(WQ, WK, WV, WO, wqt);
  }
  // fused QKV projection + RoPE: [4096][2048] x [6144][2048]^T -> Qb|Kb|Vb
  gemm8<2><<<768, 512, 0, stream>>>(xb, wqt, (void*)Qb, tp, 48);

  {
    dim3 g(64, 128), blk(32, 8);
    vtrans<<<g, blk, 0, stream>>>(Vb, VTb);
  }
  flash_attn5<<<1024, 256, 0, stream>>>(Qb, Kb, VTb, Obf);

  // output projection -> f32 d_out
  gemm8<1><<<256, 512, 0, stream>>>(Obf, wot, d_out, nullptr, 16);
}

// Round 11
// 243.137 us; speedup vs baseline: 1.1883x; 1.1883x over previous
//
#include <hip/hip_runtime.h>
#include <hip/hip_bf16.h>
#include <cstdint>
#include <cstddef>

typedef unsigned short u16;
typedef __attribute__((ext_vector_type(4))) unsigned short u16x4;
typedef __attribute__((ext_vector_type(8))) unsigned short u16x8;
typedef __attribute__((ext_vector_type(8))) __bf16 bf16x8;
typedef __attribute__((ext_vector_type(4))) float f32x4;

#define MFMA16(a, b, c) __builtin_amdgcn_mfma_f32_16x16x32_bf16((a), (b), (c), 0, 0, 0)

__device__ __forceinline__ u16 f2bf(float f) {
  uint32_t u = __builtin_bit_cast(uint32_t, f);
  u += 0x7FFFu + ((u >> 16) & 1u);
  return (u16)(u >> 16);
}
__device__ __forceinline__ float bf2f(u16 h) {
  return __builtin_bit_cast(float, (uint32_t)h << 16);
}

typedef const __attribute__((address_space(1))) void gv_t;
typedef __attribute__((address_space(3))) void lv_t;
__device__ __forceinline__ void gload16(const void* g, void* l) {
  __builtin_amdgcn_global_load_lds((gv_t*)g, (lv_t*)l, 16, 0, 0);
}

// ---------------- f32 -> bf16 convert (vectorized) ----------------
__global__ void cvt_f32_to_bf16(const float* __restrict__ in, u16* __restrict__ out, int n4) {
  int i = blockIdx.x * 256 + threadIdx.x;
  if (i >= n4) return;
  float4 v = ((const float4*)in)[i];
  u16x4 o;
  o[0] = f2bf(v.x); o[1] = f2bf(v.y); o[2] = f2bf(v.z); o[3] = f2bf(v.w);
  ((u16x4*)out)[i] = o;
}

// ------------- transpose + convert x4: W[2048][2048] f32 -> Wt bf16 [N][K], z picks W -------------
__global__ void transpose_cvt4(const float* __restrict__ w0, const float* __restrict__ w1,
                               const float* __restrict__ w2, const float* __restrict__ w3,
                               u16* __restrict__ outbase) {
  __shared__ float tile[32][33];
  const int z = blockIdx.z;
  const float* in = (z == 0) ? w0 : (z == 1) ? w1 : (z == 2) ? w2 : w3;
  u16* out = outbase + (size_t)z * 4194304;  // 2048*2048 each
  const int bx = blockIdx.x, by = blockIdx.y;
  const int tx = threadIdx.x, ty = threadIdx.y;
#pragma unroll
  for (int i = 0; i < 32; i += 8)
    tile[ty + i][tx] = in[(size_t)(by * 32 + ty + i) * 2048 + bx * 32 + tx];
  __syncthreads();
#pragma unroll
  for (int i = 0; i < 32; i += 8)
    out[(size_t)(bx * 32 + ty + i) * 2048 + by * 32 + tx] = f2bf(tile[tx][ty + i]);
}

// ------------- per-head transpose of V: bf16 [B*S][H*dk] -> VT [B,H,dk,S] -------------
__global__ void vtrans(const u16* __restrict__ in, u16* __restrict__ out) {
  __shared__ u16 tile[32][34];
  const int bx = blockIdx.x, by = blockIdx.y;
  const int tx = threadIdx.x, ty = threadIdx.y;
#pragma unroll
  for (int i = 0; i < 32; i += 8)
    tile[ty + i][tx] = in[(size_t)(by * 32 + ty + i) * 2048 + bx * 32 + tx];
  __syncthreads();
#pragma unroll
  for (int i = 0; i < 32; i += 8) {
    const int c = bx * 32 + ty + i;      // 0..2047 = h*128 + d
    const int token = by * 32 + tx;      // 0..4095 = b*2048 + s
    out[(((size_t)(token >> 11) * 16 + (c >> 7)) * 128 + (c & 127)) * 2048 + (token & 2047)] =
        tile[tx][ty + i];
  }
}

// ============ merged-phase GEMM: C[M,*] = A[M,2048] * Bt[*,2048]^T ============
// BM=256, BN=128, BK=64, 512 threads (8 waves: 4M x 2N, per-wave 64x64).
// 3-deep LDS pipeline, counted vmcnt(6), ONE barrier per K-tile. T2 swizzle both-sides.
// L2 raster: each XCD owns nbn/8 B-columns x ALL bm rows.
// MODE 1: f32 C [M][2048].  MODE 2: bf16 QKV split + FUSED RoPE (no-scratch __sinf/__cosf).
template <int MODE>
__global__ __launch_bounds__(512, 1) void gemm8(const u16* __restrict__ A,
                                                const u16* __restrict__ Bt,
                                                void* __restrict__ Cv,
                                                const int* __restrict__ pos, int nbn) {
  constexpr int K = 2048;
  __shared__ __align__(16) u16 lds[73728];  // 3 x (A 32KB + B 16KB) = 144KB
  const int tid = threadIdx.x, lane = tid & 63;
  const int lo16 = lane & 15, hi = lane >> 4;
  const int wid = tid >> 6;
  const int wr = wid >> 1, wc = wid & 1;

  // XCD-owned B-column raster
  const int xcd = (int)blockIdx.x & 7;
  const int idx = (int)blockIdx.x >> 3;
  const int cpx = nbn >> 3;
  const int bn = (xcd * cpx + idx % cpx) * 128;
  const int bm = (idx / cpx) * 256;

  const int srow = tid >> 3;
  const int scol = ((tid & 7) ^ (srow & 7)) * 8;  // pre-swizzled source col (elements)
  const u16* Arow = A + (size_t)(bm + srow) * K + scol;
  const u16* Brow = Bt + (size_t)(bn + srow) * K + scol;
  char* dstbase = (char*)lds + tid * 16;

#define STG_A(qb_, t_, r_) \
  gload16(Arow + (size_t)(r_) * 64 * K + (t_) * 64, dstbase + (qb_) * 49152 + (r_) * 8192)
#define STG_B(qb_, t_, r_) \
  gload16(Brow + (size_t)(r_) * 64 * K + (t_) * 64, dstbase + (qb_) * 49152 + 32768 + (r_) * 8192)

  f32x4 acc[4][4];
  const f32x4 z4 = {0.f, 0.f, 0.f, 0.f};
#pragma unroll
  for (int m = 0; m < 4; ++m)
#pragma unroll
    for (int n = 0; n < 4; ++n) acc[m][n] = z4;

  const int xork = lo16 & 7;
  const int aRow = (wr * 64 + lo16) * 128;
  const int bRow = 32768 + (wc * 64 + lo16) * 128;
  const int x0 = ((hi ^ xork)) << 4;
  const int x1 = (((4 + hi) ^ xork)) << 4;

  STG_A(0, 0, 0); STG_A(0, 0, 1); STG_A(0, 0, 2); STG_A(0, 0, 3);
  STG_B(0, 0, 0); STG_B(0, 0, 1);
  STG_A(1, 1, 0); STG_A(1, 1, 1); STG_A(1, 1, 2); STG_A(1, 1, 3);
  STG_B(1, 1, 0); STG_B(1, 1, 1);

  int q = 0;
  for (int t = 0; t < 32; ++t) {
    if (t < 31) {
      asm volatile("s_waitcnt vmcnt(6)" ::: "memory");
    } else {
      asm volatile("s_waitcnt vmcnt(0)" ::: "memory");
    }
    __builtin_amdgcn_s_barrier();
    __builtin_amdgcn_sched_barrier(0);
    const char* Aq = (const char*)lds + q * 49152;
    const int q2 = (q == 0) ? 2 : q - 1;

    bf16x8 a0[4], b0[4], a1[4], b1[4];
#pragma unroll
    for (int m = 0; m < 4; ++m) a0[m] = *(const bf16x8*)(Aq + aRow + m * 2048 + x0);
#pragma unroll
    for (int n = 0; n < 4; ++n) b0[n] = *(const bf16x8*)(Aq + bRow + n * 2048 + x0);
#pragma unroll
    for (int m = 0; m < 4; ++m) a1[m] = *(const bf16x8*)(Aq + aRow + m * 2048 + x1);
#pragma unroll
    for (int n = 0; n < 4; ++n) b1[n] = *(const bf16x8*)(Aq + bRow + n * 2048 + x1);

    if (t < 30) {
      STG_A(q2, t + 2, 0); STG_A(q2, t + 2, 1); STG_A(q2, t + 2, 2); STG_A(q2, t + 2, 3);
      STG_B(q2, t + 2, 0); STG_B(q2, t + 2, 1);
    }

    __builtin_amdgcn_s_setprio(1);
#pragma unroll
    for (int m = 0; m < 4; ++m)
#pragma unroll
      for (int n = 0; n < 4; ++n) acc[m][n] = MFMA16(a0[m], b0[n], acc[m][n]);
#pragma unroll
    for (int m = 0; m < 4; ++m)
#pragma unroll
      for (int n = 0; n < 4; ++n) acc[m][n] = MFMA16(a1[m], b1[n], acc[m][n]);
    __builtin_amdgcn_s_setprio(0);
    q = (q == 2) ? 0 : q + 1;
  }
#undef STG_A
#undef STG_B

  // ---- epilogue ----
  if constexpr (MODE == 2) {
    const int sect = bn >> 11;  // 0=Q, 1=K, 2=V
    u16* Cq = (u16*)Cv + (size_t)sect * 8388608;
    const int cb = (bn & 2047) + wc * 64;
    if (sect < 2) {
      const float qsc = (sect == 0) ? 0.08838834764831845f : 1.0f;
      float freq[4];
#pragma unroll
      for (int n = 0; n < 4; ++n) {
        const int c = cb + n * 16 + lo16;
        freq[n] = exp2f((float)((c & 127) >> 1) * -0.2076205059304601f);
      }
      const float sg = (lo16 & 1) ? 1.f : -1.f;
#pragma unroll
      for (int m = 0; m < 4; ++m) {
        const int row = bm + wr * 64 + m * 16 + hi * 4;
#pragma unroll
        for (int r = 0; r < 4; ++r) {
          const float p = (float)pos[row + r];
#pragma unroll
          for (int n = 0; n < 4; ++n) {
            const float ang = p * freq[n];
            const float sn = __sinf(ang);
            const float cs = __cosf(ang);
            const float v = acc[m][n][r];
            const float pv = __shfl_xor(v, 1);
            Cq[(size_t)(row + r) * 2048 + cb + n * 16 + lo16] =
                f2bf((v * cs + sg * pv * sn) * qsc);
          }
        }
      }
    } else {
#pragma unroll
      for (int m = 0; m < 4; ++m)
#pragma unroll
        for (int n = 0; n < 4; ++n)
#pragma unroll
          for (int r = 0; r < 4; ++r)
            Cq[(size_t)(bm + wr * 64 + m * 16 + hi * 4 + r) * 2048 + cb + n * 16 + lo16] =
                f2bf(acc[m][n][r]);
    }
  } else {
    float* C = (float*)Cv;
    const int cb = bn + wc * 64;
#pragma unroll
    for (int m = 0; m < 4; ++m)
#pragma unroll
      for (int n = 0; n < 4; ++n)
#pragma unroll
        for (int r = 0; r < 4; ++r)
          C[(size_t)(bm + wr * 64 + m * 16 + hi * 4 + r) * 2048 + cb + n * 16 + lo16] =
              acc[m][n][r];
  }
}

// ------------- causal flash attention v6: QTILE=64, KVBLK=64, double-buffered -------------
// = round-9's flash_attn4 (complementary pair of q-tiles, 33 steps/block) +
//   (a) deferred l-reduce: l_r per-lane partial, 16-lane reduce ONCE in epilogue;
//   (b) defer-max (T13, THR=8): skip max-reduce + rescale when no row grew past m+8.
__global__ __launch_bounds__(256, 2) void flash_attn4(const u16* __restrict__ Qb,
                                                      const u16* __restrict__ Kb,
                                                      const u16* __restrict__ VT,
                                                      u16* __restrict__ Ob) {
  constexpr int S = 2048, HD = 2048;
  const int g = (int)blockIdx.x;
  const int xcd = g & 7, slot = g >> 3;      // 64 slots per XCD
  const int bh = xcd * 4 + (slot & 3);       // 4 heads per XCD
  const int pairid = slot >> 2;              // 0..15
  const int b = bh >> 4, h = bh & 15;
  const int tid = threadIdx.x, lane = tid & 63, wid = tid >> 6;

  __shared__ u16 Ks[2][64 * 128];
  __shared__ u16 Vs[2][128 * 64];
  __shared__ u16 Ps[4][16 * 64];

  const size_t base = (size_t)b * S * HD + (size_t)h * 128;
  const u16* Qp = Qb + base;
  const u16* Kp = Kb + base;
  const u16* VTp = VT + (size_t)bh * 128 * S;
  u16* Op = Ob + base;

  const f32x4 z4 = {0.f, 0.f, 0.f, 0.f};
  const int kKv = (lane >> 4);
  const int kC16 = (lane & 15);
  const int vD = (lane >> 3);
  const int vC16 = (lane & 7);

#define STAGE(pb, kv0_)                                                                   \
  {                                                                                       \
    _Pragma("unroll") for (int c = 0; c < 4; ++c) {                                       \
      const int ch = wid * 4 + c;                                                         \
      {                                                                                   \
        const int kv = ch * 4 + kKv;                                                      \
        const int c16 = kC16 ^ (kv & 7);                                                  \
        gload16(Kp + (size_t)((kv0_) + kv) * HD + c16 * 8, (char*)Ks[pb] + ch * 1024);    \
      }                                                                                   \
      {                                                                                   \
        const int d = ch * 8 + vD;                                                        \
        const int c16 = vC16 ^ (d & 7);                                                   \
        gload16(VTp + (size_t)d * S + (kv0_) + c16 * 8, (char*)Vs[pb] + ch * 1024);       \
      }                                                                                   \
    }                                                                                     \
  }

#pragma unroll
  for (int half = 0; half < 2; ++half) {
    const int qt = half ? pairid : 31 - pairid;  // heavy tile first
    const int q0 = qt * 64;

    bf16x8 qf[4];
    {
      const int qr = q0 + wid * 16 + (lane & 15);
      const int kc = (lane >> 4) * 8;
#pragma unroll
      for (int kb = 0; kb < 4; ++kb)
        qf[kb] = *(const bf16x8*)(Qp + (size_t)qr * HD + kb * 32 + kc);
    }

    f32x4 accO[8];
#pragma unroll
    for (int d = 0; d < 8; ++d) accO[d] = z4;
    float m_r[4] = {-INFINITY, -INFINITY, -INFINITY, -INFINITY};
    float l_r[4] = {0.f, 0.f, 0.f, 0.f};  // PER-LANE partial sums (reduced in epilogue)

    STAGE(0, 0);
    __syncthreads();

    for (int t = 0; t <= qt; ++t) {
      const int cur = t & 1;
      const int kv0 = t * 64;
      if (t < qt) STAGE(cur ^ 1, kv0 + 64);

      const u16* Ksc = Ks[cur];
      const u16* Vsc = Vs[cur];
      f32x4 accS[4];
#pragma unroll
      for (int nb = 0; nb < 4; ++nb) accS[nb] = z4;

      // ---- S = Q K^T ----
      __builtin_amdgcn_s_setprio(1);
#pragma unroll
      for (int nb = 0; nb < 4; ++nb) {
        const int kv = nb * 16 + (lane & 15);
#pragma unroll
        for (int kb = 0; kb < 4; ++kb) {
          const int c16 = (kb * 4 + (lane >> 4)) ^ (kv & 7);
          bf16x8 kf = *(const bf16x8*)((char*)Ksc + kv * 256 + c16 * 16);
          accS[nb] = MFMA16(qf[kb], kf, accS[nb]);
        }
      }
      __builtin_amdgcn_s_setprio(0);

      // ---- causal mask (diagonal step only) ----
      if (t == qt) {
#pragma unroll
        for (int nb = 0; nb < 4; ++nb) {
          const int kv = kv0 + nb * 16 + (lane & 15);
          const int qrow = q0 + wid * 16 + (lane >> 4) * 4;
#pragma unroll
          for (int j = 0; j < 4; ++j)
            if (kv > qrow + j) accS[nb][j] = -INFINITY;
        }
      }

      // ---- defer-max check (T13, THR=8): local per-row max over this lane's 4 slots ----
      float lm[4];
#pragma unroll
      for (int j = 0; j < 4; ++j)
        lm[j] = fmaxf(fmaxf(accS[0][j], accS[1][j]), fmaxf(accS[2][j], accS[3][j]));
      const bool ok = (lm[0] <= m_r[0] + 8.f) && (lm[1] <= m_r[1] + 8.f) &&
                      (lm[2] <= m_r[2] + 8.f) && (lm[3] <= m_r[3] + 8.f);
      if (!__all(ok)) {
        // slow path: full 16-lane max reduce + rescale of l and O
#pragma unroll
        for (int j = 0; j < 4; ++j) {
          float mx = lm[j];
#pragma unroll
          for (int off = 1; off < 16; off <<= 1) mx = fmaxf(mx, __shfl_xor(mx, off));
          const float mn = fmaxf(m_r[j], mx);
          const float sc = __expf(m_r[j] - mn);
          m_r[j] = mn;
          l_r[j] *= sc;
#pragma unroll
          for (int db = 0; db < 8; ++db) accO[db][j] *= sc;
        }
      }

      // ---- exponentiate vs (possibly deferred) m_r, per-lane partial sum, P write ----
      u16* Pw = &Ps[wid][0];
#pragma unroll
      for (int j = 0; j < 4; ++j) {
        float s = 0.f;
#pragma unroll
        for (int nb = 0; nb < 4; ++nb) {
          const float p = __expf(accS[nb][j] - m_r[j]);
          accS[nb][j] = p;
          s += p;
        }
        l_r[j] += s;
        const int ql = (lane >> 4) * 4 + j;
#pragma unroll
        for (int nb = 0; nb < 4; ++nb) {
          const int col = nb * 16 + (lane & 15);
          const int byteoff = ql * 128 + ((((col >> 3) ^ (ql & 7))) << 4) + (col & 7) * 2;
          *(u16*)((char*)Pw + byteoff) = f2bf(accS[nb][j]);
        }
      }

      // ---- O += P V ----
#pragma unroll
      for (int kb2 = 0; kb2 < 2; ++kb2) {
        const int ql = lane & 15;
        const int c16a = (kb2 * 4 + (lane >> 4)) ^ (ql & 7);
        bf16x8 pa = *(const bf16x8*)((char*)Pw + ql * 128 + c16a * 16);
        __builtin_amdgcn_s_setprio(1);
#pragma unroll
        for (int db = 0; db < 8; ++db) {
          const int d = db * 16 + (lane & 15);
          const int c16 = (kb2 * 4 + (lane >> 4)) ^ (d & 7);
          bf16x8 vf = *(const bf16x8*)((char*)Vsc + d * 128 + c16 * 16);
          accO[db] = MFMA16(pa, vf, accO[db]);
        }
        __builtin_amdgcn_s_setprio(0);
      }
      __syncthreads();
    }

    // ---- epilogue: reduce per-lane l across the 16-lane group, normalize, store ----
    float inv[4];
#pragma unroll
    for (int j = 0; j < 4; ++j) {
      float l = l_r[j];
#pragma unroll
      for (int off = 1; off < 16; off <<= 1) l += __shfl_xor(l, off);
      inv[j] = 1.f / l;
    }
#pragma unroll
    for (int db = 0; db < 8; ++db)
#pragma unroll
      for (int j = 0; j < 4; ++j) {
        const int row = q0 + wid * 16 + (lane >> 4) * 4 + j;
        Op[(size_t)row * HD + db * 16 + (lane & 15)] = f2bf(accO[db][j] * inv[j]);
      }
  }
#undef STAGE
}

extern "C" void kernel_launch(void* const* d_in, const int* in_sizes, int n_in,
                              void* d_out, int out_size, void* d_ws, size_t ws_size,
                              hipStream_t stream) {
  const float* x  = (const float*)d_in[0];
  const int*   tp = (const int*)d_in[1];
  const float* WQ = (const float*)d_in[2];
  const float* WK = (const float*)d_in[3];
  const float* WV = (const float*)d_in[4];
  const float* WO = (const float*)d_in[5];

  const size_t MB = 1024 * 1024;
  if (ws_size < 112 * MB) return;
  char* ws = (char*)d_ws;
  u16* xb  = (u16*)(ws + 0 * MB);
  u16* wqt = (u16*)(ws + 16 * MB);   // wqt/wkt/wvt/wot contiguous, 8MB each
  u16* wot = (u16*)(ws + 40 * MB);
  u16* Qb  = (u16*)(ws + 48 * MB);   // Qb/Kb/Vb contiguous, 16MB apart
  u16* Kb  = (u16*)(ws + 64 * MB);
  u16* Vb  = (u16*)(ws + 80 * MB);
  u16* Obf = (u16*)(ws + 96 * MB);
  u16* VTb = xb;  // V^T [B,H,dk,S] (xb dead after projections)

  cvt_f32_to_bf16<<<8192, 256, 0, stream>>>(x, xb, 2097152);
  {
    dim3 g(64, 64, 4), blk(32, 8);
    transpose_cvt4<<<g, blk, 0, stream>>>(WQ, WK, WV, WO, wqt);
  }
  // fused QKV projection + RoPE: [4096][2048] x [6144][2048]^T -> Qb|Kb|Vb
  gemm8<2><<<768, 512, 0, stream>>>(xb, wqt, (void*)Qb, tp, 48);

  {
    dim3 g(64, 128), blk(32, 8);
    vtrans<<<g, blk, 0, stream>>>(Vb, VTb);
  }
  flash_attn4<<<512, 256, 0, stream>>>(Qb, Kb, VTb, Obf);

  // output projection -> f32 d_out
  gemm8<1><<<256, 512, 0, stream>>>(Obf, wot, d_out, nullptr, 16);
}

// Round 12
// 238.072 us; speedup vs baseline: 1.2136x; 1.0213x over previous
//
#include <hip/hip_runtime.h>
#include <hip/hip_bf16.h>
#include <cstdint>
#include <cstddef>

typedef unsigned short u16;
typedef __attribute__((ext_vector_type(4))) unsigned short u16x4;
typedef __attribute__((ext_vector_type(8))) unsigned short u16x8;
typedef __attribute__((ext_vector_type(8))) __bf16 bf16x8;
typedef __attribute__((ext_vector_type(4))) float f32x4;

#define MFMA16(a, b, c) __builtin_amdgcn_mfma_f32_16x16x32_bf16((a), (b), (c), 0, 0, 0)

__device__ __forceinline__ u16 f2bf(float f) {
  uint32_t u = __builtin_bit_cast(uint32_t, f);
  u += 0x7FFFu + ((u >> 16) & 1u);
  return (u16)(u >> 16);
}
__device__ __forceinline__ float bf2f(u16 h) {
  return __builtin_bit_cast(float, (uint32_t)h << 16);
}

typedef const __attribute__((address_space(1))) void gv_t;
typedef __attribute__((address_space(3))) void lv_t;
__device__ __forceinline__ void gload16(const void* g, void* l) {
  __builtin_amdgcn_global_load_lds((gv_t*)g, (lv_t*)l, 16, 0, 0);
}

// ---------------- f32 -> bf16 convert (vectorized) ----------------
__global__ void cvt_f32_to_bf16(const float* __restrict__ in, u16* __restrict__ out, int n4) {
  int i = blockIdx.x * 256 + threadIdx.x;
  if (i >= n4) return;
  float4 v = ((const float4*)in)[i];
  u16x4 o;
  o[0] = f2bf(v.x); o[1] = f2bf(v.y); o[2] = f2bf(v.z); o[3] = f2bf(v.w);
  ((u16x4*)out)[i] = o;
}

// ------------- transpose + convert x4: W[2048][2048] f32 -> Wt bf16 [N][K], z picks W -------------
__global__ void transpose_cvt4(const float* __restrict__ w0, const float* __restrict__ w1,
                               const float* __restrict__ w2, const float* __restrict__ w3,
                               u16* __restrict__ outbase) {
  __shared__ float tile[32][33];
  const int z = blockIdx.z;
  const float* in = (z == 0) ? w0 : (z == 1) ? w1 : (z == 2) ? w2 : w3;
  u16* out = outbase + (size_t)z * 4194304;  // 2048*2048 each
  const int bx = blockIdx.x, by = blockIdx.y;
  const int tx = threadIdx.x, ty = threadIdx.y;
#pragma unroll
  for (int i = 0; i < 32; i += 8)
    tile[ty + i][tx] = in[(size_t)(by * 32 + ty + i) * 2048 + bx * 32 + tx];
  __syncthreads();
#pragma unroll
  for (int i = 0; i < 32; i += 8)
    out[(size_t)(bx * 32 + ty + i) * 2048 + by * 32 + tx] = f2bf(tile[tx][ty + i]);
}

// ============ merged-phase GEMM: C[M,*] = A[M,2048] * Bt[*,2048]^T ============
// BM=256, BN=128, BK=64, 512 threads (8 waves: 4M x 2N, per-wave 64x64).
// 3-deep LDS pipeline, counted vmcnt(6), ONE barrier per K-tile. T2 swizzle both-sides.
// L2 raster: each XCD owns nbn/8 B-columns x ALL bm rows.
// MODE 1: f32 C [M][2048].
// MODE 2: bf16 QKV: Q/K sections get FUSED RoPE; V section written TRANSPOSED to VT
//         (LDS transpose in epilogue) -- vtrans kernel eliminated.
template <int MODE>
__global__ __launch_bounds__(512, 1) void gemm8(const u16* __restrict__ A,
                                                const u16* __restrict__ Bt,
                                                void* __restrict__ Cv,
                                                const int* __restrict__ pos, int nbn) {
  constexpr int K = 2048;
  __shared__ __align__(16) u16 lds[73728];  // 3 x (A 32KB + B 16KB) = 144KB
  const int tid = threadIdx.x, lane = tid & 63;
  const int lo16 = lane & 15, hi = lane >> 4;
  const int wid = tid >> 6;
  const int wr = wid >> 1, wc = wid & 1;

  // XCD-owned B-column raster
  const int xcd = (int)blockIdx.x & 7;
  const int idx = (int)blockIdx.x >> 3;
  const int cpx = nbn >> 3;
  const int bn = (xcd * cpx + idx % cpx) * 128;
  const int bm = (idx / cpx) * 256;

  const int srow = tid >> 3;
  const int scol = ((tid & 7) ^ (srow & 7)) * 8;  // pre-swizzled source col (elements)
  const u16* Arow = A + (size_t)(bm + srow) * K + scol;
  const u16* Brow = Bt + (size_t)(bn + srow) * K + scol;
  char* dstbase = (char*)lds + tid * 16;

#define STG_A(qb_, t_, r_) \
  gload16(Arow + (size_t)(r_) * 64 * K + (t_) * 64, dstbase + (qb_) * 49152 + (r_) * 8192)
#define STG_B(qb_, t_, r_) \
  gload16(Brow + (size_t)(r_) * 64 * K + (t_) * 64, dstbase + (qb_) * 49152 + 32768 + (r_) * 8192)

  f32x4 acc[4][4];
  const f32x4 z4 = {0.f, 0.f, 0.f, 0.f};
#pragma unroll
  for (int m = 0; m < 4; ++m)
#pragma unroll
    for (int n = 0; n < 4; ++n) acc[m][n] = z4;

  const int xork = lo16 & 7;
  const int aRow = (wr * 64 + lo16) * 128;
  const int bRow = 32768 + (wc * 64 + lo16) * 128;
  const int x0 = ((hi ^ xork)) << 4;
  const int x1 = (((4 + hi) ^ xork)) << 4;

  STG_A(0, 0, 0); STG_A(0, 0, 1); STG_A(0, 0, 2); STG_A(0, 0, 3);
  STG_B(0, 0, 0); STG_B(0, 0, 1);
  STG_A(1, 1, 0); STG_A(1, 1, 1); STG_A(1, 1, 2); STG_A(1, 1, 3);
  STG_B(1, 1, 0); STG_B(1, 1, 1);

  int q = 0;
  for (int t = 0; t < 32; ++t) {
    if (t < 31) {
      asm volatile("s_waitcnt vmcnt(6)" ::: "memory");
    } else {
      asm volatile("s_waitcnt vmcnt(0)" ::: "memory");
    }
    __builtin_amdgcn_s_barrier();
    __builtin_amdgcn_sched_barrier(0);
    const char* Aq = (const char*)lds + q * 49152;
    const int q2 = (q == 0) ? 2 : q - 1;

    bf16x8 a0[4], b0[4], a1[4], b1[4];
#pragma unroll
    for (int m = 0; m < 4; ++m) a0[m] = *(const bf16x8*)(Aq + aRow + m * 2048 + x0);
#pragma unroll
    for (int n = 0; n < 4; ++n) b0[n] = *(const bf16x8*)(Aq + bRow + n * 2048 + x0);
#pragma unroll
    for (int m = 0; m < 4; ++m) a1[m] = *(const bf16x8*)(Aq + aRow + m * 2048 + x1);
#pragma unroll
    for (int n = 0; n < 4; ++n) b1[n] = *(const bf16x8*)(Aq + bRow + n * 2048 + x1);

    if (t < 30) {
      STG_A(q2, t + 2, 0); STG_A(q2, t + 2, 1); STG_A(q2, t + 2, 2); STG_A(q2, t + 2, 3);
      STG_B(q2, t + 2, 0); STG_B(q2, t + 2, 1);
    }

    __builtin_amdgcn_s_setprio(1);
#pragma unroll
    for (int m = 0; m < 4; ++m)
#pragma unroll
      for (int n = 0; n < 4; ++n) acc[m][n] = MFMA16(a0[m], b0[n], acc[m][n]);
#pragma unroll
    for (int m = 0; m < 4; ++m)
#pragma unroll
      for (int n = 0; n < 4; ++n) acc[m][n] = MFMA16(a1[m], b1[n], acc[m][n]);
    __builtin_amdgcn_s_setprio(0);
    q = (q == 2) ? 0 : q + 1;
  }
#undef STG_A
#undef STG_B

  // ---- epilogue ----
  if constexpr (MODE == 2) {
    const int sect = bn >> 11;  // 0=Q, 1=K, 2=V (buffers 16MB apart = 8388608 u16)
    u16* Cq = (u16*)Cv + (size_t)sect * 8388608;
    const int cb = (bn & 2047) + wc * 64;
    if (sect < 2) {
      const float qsc = (sect == 0) ? 0.08838834764831845f : 1.0f;
      float freq[4];
#pragma unroll
      for (int n = 0; n < 4; ++n) {
        const int c = cb + n * 16 + lo16;
        freq[n] = exp2f((float)((c & 127) >> 1) * -0.2076205059304601f);
      }
      const float sg = (lo16 & 1) ? 1.f : -1.f;
#pragma unroll
      for (int m = 0; m < 4; ++m) {
        const int row = bm + wr * 64 + m * 16 + hi * 4;
#pragma unroll
        for (int r = 0; r < 4; ++r) {
          const float p = (float)pos[row + r];
#pragma unroll
          for (int n = 0; n < 4; ++n) {
            const float ang = p * freq[n];
            const float sn = __sinf(ang);
            const float cs = __cosf(ang);
            const float v = acc[m][n][r];
            const float pv = __shfl_xor(v, 1);
            Cq[(size_t)(row + r) * 2048 + cb + n * 16 + lo16] =
                f2bf((v * cs + sg * pv * sn) * qsc);
          }
        }
      }
    } else {
      // ---- V section: LDS-transpose and write VT [B,H,dk,S] directly ----
      __syncthreads();  // all waves done with staging LDS
      // write acc -> lds as [d][tok], stride 260 (keeps 8B alignment, spreads banks)
#pragma unroll
      for (int m = 0; m < 4; ++m) {
#pragma unroll
        for (int n = 0; n < 4; ++n) {
          const int d = wc * 64 + n * 16 + lo16;
          const int tokb = wr * 64 + m * 16 + hi * 4;
#pragma unroll
          for (int r = 0; r < 4; ++r)
            lds[d * 260 + tokb + r] = f2bf(acc[m][n][r]);
        }
      }
      __syncthreads();
      // read d-rows and store coalesced: VT idx = ((b*16+h)*128+d)*2048 + s
      const int b = bm >> 11, hh = (bn & 2047) >> 7;
      u16* vt = Cq + ((size_t)((b * 16 + hh) * 128)) * 2048 + (bm & 2047);
#pragma unroll
      for (int j = 0; j < 4; ++j) {
        const int d = (tid >> 4) + j * 32;
        const int t0 = (tid & 15) * 16;
        const u16* src = lds + d * 260 + t0;
        u16* dst = vt + (size_t)d * 2048 + t0;
#pragma unroll
        for (int w = 0; w < 4; ++w)
          *(u16x4*)(dst + w * 4) = *(const u16x4*)(src + w * 4);
      }
    }
  } else {
    float* C = (float*)Cv;
    const int cb = bn + wc * 64;
#pragma unroll
    for (int m = 0; m < 4; ++m)
#pragma unroll
      for (int n = 0; n < 4; ++n)
#pragma unroll
        for (int r = 0; r < 4; ++r)
          C[(size_t)(bm + wr * 64 + m * 16 + hi * 4 + r) * 2048 + cb + n * 16 + lo16] =
              acc[m][n][r];
  }
}

// ------------- causal flash attention v7: QTILE=64, KVBLK=64, double-buffered -------------
// round-11 structure (complementary q-tile pair, defer-max, deferred l-reduce) +
// counted-vmcnt pipeline: raw s_barrier (no drain), s_waitcnt vmcnt(8) waits only
// tile-t's own loads -- prefetch for t+1 stays in flight across barriers (T4).
__global__ __launch_bounds__(256, 2) void flash_attn4(const u16* __restrict__ Qb,
                                                      const u16* __restrict__ Kb,
                                                      const u16* __restrict__ VT,
                                                      u16* __restrict__ Ob) {
  constexpr int S = 2048, HD = 2048;
  const int g = (int)blockIdx.x;
  const int xcd = g & 7, slot = g >> 3;      // 64 slots per XCD
  const int bh = xcd * 4 + (slot & 3);       // 4 heads per XCD
  const int pairid = slot >> 2;              // 0..15
  const int b = bh >> 4, h = bh & 15;
  const int tid = threadIdx.x, lane = tid & 63, wid = tid >> 6;

  __shared__ u16 Ks[2][64 * 128];
  __shared__ u16 Vs[2][128 * 64];
  __shared__ u16 Ps[4][16 * 64];

  const size_t base = (size_t)b * S * HD + (size_t)h * 128;
  const u16* Qp = Qb + base;
  const u16* Kp = Kb + base;
  const u16* VTp = VT + (size_t)bh * 128 * S;
  u16* Op = Ob + base;

  const f32x4 z4 = {0.f, 0.f, 0.f, 0.f};
  const int kKv = (lane >> 4);
  const int kC16 = (lane & 15);
  const int vD = (lane >> 3);
  const int vC16 = (lane & 7);

#define STAGE(pb, kv0_)                                                                   \
  {                                                                                       \
    _Pragma("unroll") for (int c = 0; c < 4; ++c) {                                       \
      const int ch = wid * 4 + c;                                                         \
      {                                                                                   \
        const int kv = ch * 4 + kKv;                                                      \
        const int c16 = kC16 ^ (kv & 7);                                                  \
        gload16(Kp + (size_t)((kv0_) + kv) * HD + c16 * 8, (char*)Ks[pb] + ch * 1024);    \
      }                                                                                   \
      {                                                                                   \
        const int d = ch * 8 + vD;                                                        \
        const int c16 = vC16 ^ (d & 7);                                                   \
        gload16(VTp + (size_t)d * S + (kv0_) + c16 * 8, (char*)Vs[pb] + ch * 1024);       \
      }                                                                                   \
    }                                                                                     \
  }

#pragma unroll
  for (int half = 0; half < 2; ++half) {
    const int qt = half ? pairid : 31 - pairid;  // heavy tile first
    const int q0 = qt * 64;

    bf16x8 qf[4];
    {
      const int qr = q0 + wid * 16 + (lane & 15);
      const int kc = (lane >> 4) * 8;
#pragma unroll
      for (int kb = 0; kb < 4; ++kb)
        qf[kb] = *(const bf16x8*)(Qp + (size_t)qr * HD + kb * 32 + kc);
    }

    f32x4 accO[8];
#pragma unroll
    for (int d = 0; d < 8; ++d) accO[d] = z4;
    float m_r[4] = {-INFINITY, -INFINITY, -INFINITY, -INFINITY};
    float l_r[4] = {0.f, 0.f, 0.f, 0.f};  // per-lane partials, reduced in epilogue

    STAGE(0, 0);  // 8 loads in flight

    for (int t = 0; t <= qt; ++t) {
      const int cur = t & 1;
      const int kv0 = t * 64;
      if (t < qt) {
        STAGE(cur ^ 1, kv0 + 64);                          // +8 loads (tile t+1)
        asm volatile("s_waitcnt vmcnt(8)" ::: "memory");   // wait tile t's 8 only
      } else {
        asm volatile("s_waitcnt vmcnt(0)" ::: "memory");
      }
      __builtin_amdgcn_s_barrier();       // all waves: tile t resident
      __builtin_amdgcn_sched_barrier(0);

      const u16* Ksc = Ks[cur];
      const u16* Vsc = Vs[cur];
      f32x4 accS[4];
#pragma unroll
      for (int nb = 0; nb < 4; ++nb) accS[nb] = z4;

      // ---- S = Q K^T ----
      __builtin_amdgcn_s_setprio(1);
#pragma unroll
      for (int nb = 0; nb < 4; ++nb) {
        const int kv = nb * 16 + (lane & 15);
#pragma unroll
        for (int kb = 0; kb < 4; ++kb) {
          const int c16 = (kb * 4 + (lane >> 4)) ^ (kv & 7);
          bf16x8 kf = *(const bf16x8*)((char*)Ksc + kv * 256 + c16 * 16);
          accS[nb] = MFMA16(qf[kb], kf, accS[nb]);
        }
      }
      __builtin_amdgcn_s_setprio(0);

      // ---- causal mask (diagonal step only) ----
      if (t == qt) {
#pragma unroll
        for (int nb = 0; nb < 4; ++nb) {
          const int kv = kv0 + nb * 16 + (lane & 15);
          const int qrow = q0 + wid * 16 + (lane >> 4) * 4;
#pragma unroll
          for (int j = 0; j < 4; ++j)
            if (kv > qrow + j) accS[nb][j] = -INFINITY;
        }
      }

      // ---- defer-max (T13, THR=8) ----
      float lm[4];
#pragma unroll
      for (int j = 0; j < 4; ++j)
        lm[j] = fmaxf(fmaxf(accS[0][j], accS[1][j]), fmaxf(accS[2][j], accS[3][j]));
      const bool ok = (lm[0] <= m_r[0] + 8.f) && (lm[1] <= m_r[1] + 8.f) &&
                      (lm[2] <= m_r[2] + 8.f) && (lm[3] <= m_r[3] + 8.f);
      if (!__all(ok)) {
#pragma unroll
        for (int j = 0; j < 4; ++j) {
          float mx = lm[j];
#pragma unroll
          for (int off = 1; off < 16; off <<= 1) mx = fmaxf(mx, __shfl_xor(mx, off));
          const float mn = fmaxf(m_r[j], mx);
          const float sc = __expf(m_r[j] - mn);
          m_r[j] = mn;
          l_r[j] *= sc;
#pragma unroll
          for (int db = 0; db < 8; ++db) accO[db][j] *= sc;
        }
      }

      // ---- exponentiate, per-lane partial sum, P write ----
      u16* Pw = &Ps[wid][0];
#pragma unroll
      for (int j = 0; j < 4; ++j) {
        float s = 0.f;
#pragma unroll
        for (int nb = 0; nb < 4; ++nb) {
          const float p = __expf(accS[nb][j] - m_r[j]);
          accS[nb][j] = p;
          s += p;
        }
        l_r[j] += s;
        const int ql = (lane >> 4) * 4 + j;
#pragma unroll
        for (int nb = 0; nb < 4; ++nb) {
          const int col = nb * 16 + (lane & 15);
          const int byteoff = ql * 128 + ((((col >> 3) ^ (ql & 7))) << 4) + (col & 7) * 2;
          *(u16*)((char*)Pw + byteoff) = f2bf(accS[nb][j]);
        }
      }

      // ---- O += P V ----
#pragma unroll
      for (int kb2 = 0; kb2 < 2; ++kb2) {
        const int ql = lane & 15;
        const int c16a = (kb2 * 4 + (lane >> 4)) ^ (ql & 7);
        bf16x8 pa = *(const bf16x8*)((char*)Pw + ql * 128 + c16a * 16);
        __builtin_amdgcn_s_setprio(1);
#pragma unroll
        for (int db = 0; db < 8; ++db) {
          const int d = db * 16 + (lane & 15);
          const int c16 = (kb2 * 4 + (lane >> 4)) ^ (d & 7);
          bf16x8 vf = *(const bf16x8*)((char*)Vsc + d * 128 + c16 * 16);
          accO[db] = MFMA16(pa, vf, accO[db]);
        }
        __builtin_amdgcn_s_setprio(0);
      }
      __builtin_amdgcn_sched_barrier(0);
      __builtin_amdgcn_s_barrier();  // all waves done reading buf[cur]; no drain
    }

    // ---- epilogue: reduce per-lane l, normalize, store ----
    float inv[4];
#pragma unroll
    for (int j = 0; j < 4; ++j) {
      float l = l_r[j];
#pragma unroll
      for (int off = 1; off < 16; off <<= 1) l += __shfl_xor(l, off);
      inv[j] = 1.f / l;
    }
#pragma unroll
    for (int db = 0; db < 8; ++db)
#pragma unroll
      for (int j = 0; j < 4; ++j) {
        const int row = q0 + wid * 16 + (lane >> 4) * 4 + j;
        Op[(size_t)row * HD + db * 16 + (lane & 15)] = f2bf(accO[db][j] * inv[j]);
      }
  }
#undef STAGE
}

extern "C" void kernel_launch(void* const* d_in, const int* in_sizes, int n_in,
                              void* d_out, int out_size, void* d_ws, size_t ws_size,
                              hipStream_t stream) {
  const float* x  = (const float*)d_in[0];
  const int*   tp = (const int*)d_in[1];
  const float* WQ = (const float*)d_in[2];
  const float* WK = (const float*)d_in[3];
  const float* WV = (const float*)d_in[4];
  const float* WO = (const float*)d_in[5];

  const size_t MB = 1024 * 1024;
  if (ws_size < 112 * MB) return;
  char* ws = (char*)d_ws;
  u16* xb  = (u16*)(ws + 0 * MB);
  u16* wqt = (u16*)(ws + 16 * MB);   // wqt/wkt/wvt/wot contiguous, 8MB each
  u16* wot = (u16*)(ws + 40 * MB);
  u16* Qb  = (u16*)(ws + 48 * MB);   // Q(48MB) K(64MB) VT(80MB) -- gemm8<2> sect offsets
  u16* Kb  = (u16*)(ws + 64 * MB);
  u16* VTb = (u16*)(ws + 80 * MB);   // V written TRANSPOSED here by gemm8<2> epilogue
  u16* Obf = (u16*)(ws + 96 * MB);

  cvt_f32_to_bf16<<<8192, 256, 0, stream>>>(x, xb, 2097152);
  {
    dim3 g(64, 64, 4), blk(32, 8);
    transpose_cvt4<<<g, blk, 0, stream>>>(WQ, WK, WV, WO, wqt);
  }
  // fused QKV projection + RoPE + V-transpose: -> Qb | Kb | VTb
  gemm8<2><<<768, 512, 0, stream>>>(xb, wqt, (void*)Qb, tp, 48);

  flash_attn4<<<512, 256, 0, stream>>>(Qb, Kb, VTb, Obf);

  // output projection -> f32 d_out
  gemm8<1><<<256, 512, 0, stream>>>(Obf, wot, d_out, nullptr, 16);
}

// Round 13
// 236.438 us; speedup vs baseline: 1.2220x; 1.0069x over previous
//
#include <hip/hip_runtime.h>
#include <hip/hip_bf16.h>
#include <cstdint>
#include <cstddef>

typedef unsigned short u16;
typedef __attribute__((ext_vector_type(4))) unsigned short u16x4;
typedef __attribute__((ext_vector_type(8))) unsigned short u16x8;
typedef __attribute__((ext_vector_type(8))) __bf16 bf16x8;
typedef __attribute__((ext_vector_type(4))) float f32x4;

#define MFMA16(a, b, c) __builtin_amdgcn_mfma_f32_16x16x32_bf16((a), (b), (c), 0, 0, 0)

__device__ __forceinline__ u16 f2bf(float f) {
  uint32_t u = __builtin_bit_cast(uint32_t, f);
  u += 0x7FFFu + ((u >> 16) & 1u);
  return (u16)(u >> 16);
}
__device__ __forceinline__ float bf2f(u16 h) {
  return __builtin_bit_cast(float, (uint32_t)h << 16);
}

typedef const __attribute__((address_space(1))) void gv_t;
typedef __attribute__((address_space(3))) void lv_t;
__device__ __forceinline__ void gload16(const void* g, void* l) {
  __builtin_amdgcn_global_load_lds((gv_t*)g, (lv_t*)l, 16, 0, 0);
}

// ------- prep: z=0..3 -> transpose+cvt W[z]; z=4..5 -> x f32->bf16 (merged launch) -------
__global__ void prep(const float* __restrict__ x, const float* __restrict__ w0,
                     const float* __restrict__ w1, const float* __restrict__ w2,
                     const float* __restrict__ w3, u16* __restrict__ xb,
                     u16* __restrict__ wtbase) {
  const int z = blockIdx.z;
  const int bx = blockIdx.x, by = blockIdx.y;
  const int tx = threadIdx.x, ty = threadIdx.y;
  if (z >= 4) {
    const int i = ((z - 4) * 4096 + by * 64 + bx) * 256 + ty * 32 + tx;
    float4 v = ((const float4*)x)[i];
    u16x4 o;
    o[0] = f2bf(v.x); o[1] = f2bf(v.y); o[2] = f2bf(v.z); o[3] = f2bf(v.w);
    ((u16x4*)xb)[i] = o;
    return;
  }
  __shared__ float tile[32][33];
  const float* in = (z == 0) ? w0 : (z == 1) ? w1 : (z == 2) ? w2 : w3;
  u16* out = wtbase + (size_t)z * 4194304;
#pragma unroll
  for (int i = 0; i < 32; i += 8)
    tile[ty + i][tx] = in[(size_t)(by * 32 + ty + i) * 2048 + bx * 32 + tx];
  __syncthreads();
#pragma unroll
  for (int i = 0; i < 32; i += 8)
    out[(size_t)(bx * 32 + ty + i) * 2048 + by * 32 + tx] = f2bf(tile[tx][ty + i]);
}

// ============ phase-split GEMM: C[M,*] = A[M,2048] * Bt[*,2048]^T ============
// BM=256, BN=128, BK=64, 512 threads (8 waves: 4M x 2N, per-wave 64x64).
// 3-deep LDS pipeline, counted vmcnt(6). Per K-tile: TWO phases of 16 MFMA;
// B-frags read once (reused), phase-B A-reads issue during phase-A MFMA drain;
// stages split 3+3; mid-phase barrier gives read latency cover. T2 swizzle both-sides.
// MODE 1: f32 C.  MODE 2: bf16 QKV + fused RoPE (Q/K) + V-transpose epilogue.
template <int MODE>
__global__ __launch_bounds__(512, 1) void gemm8(const u16* __restrict__ A,
                                                const u16* __restrict__ Bt,
                                                void* __restrict__ Cv,
                                                const int* __restrict__ pos, int nbn) {
  constexpr int K = 2048;
  __shared__ __align__(16) u16 lds[73728];  // 3 x (A 32KB + B 16KB) = 144KB
  const int tid = threadIdx.x, lane = tid & 63;
  const int lo16 = lane & 15, hi = lane >> 4;
  const int wid = tid >> 6;
  const int wr = wid >> 1, wc = wid & 1;

  // XCD-owned B-column raster
  const int xcd = (int)blockIdx.x & 7;
  const int idx = (int)blockIdx.x >> 3;
  const int cpx = nbn >> 3;
  const int bn = (xcd * cpx + idx % cpx) * 128;
  const int bm = (idx / cpx) * 256;

  const int srow = tid >> 3;
  const int scol = ((tid & 7) ^ (srow & 7)) * 8;  // pre-swizzled source col
  const u16* Arow = A + (size_t)(bm + srow) * K + scol;
  const u16* Brow = Bt + (size_t)(bn + srow) * K + scol;
  char* dstbase = (char*)lds + tid * 16;

#define STG_A(qb_, t_, r_) \
  gload16(Arow + (size_t)(r_) * 64 * K + (t_) * 64, dstbase + (qb_) * 49152 + (r_) * 8192)
#define STG_B(qb_, t_, r_) \
  gload16(Brow + (size_t)(r_) * 64 * K + (t_) * 64, dstbase + (qb_) * 49152 + 32768 + (r_) * 8192)

  f32x4 acc[4][4];
  const f32x4 z4 = {0.f, 0.f, 0.f, 0.f};
#pragma unroll
  for (int m = 0; m < 4; ++m)
#pragma unroll
    for (int n = 0; n < 4; ++n) acc[m][n] = z4;

  const int xork = lo16 & 7;
  const int aRow = (wr * 64 + lo16) * 128;
  const int bRow = 32768 + (wc * 64 + lo16) * 128;
  const int x0 = ((hi ^ xork)) << 4;
  const int x1 = (((4 + hi) ^ xork)) << 4;

  // prologue: stage tiles 0 and 1 (order A0,A1,B0,A2,A3,B1 -- same 6/tile FIFO)
  STG_A(0, 0, 0); STG_A(0, 0, 1); STG_B(0, 0, 0); STG_A(0, 0, 2); STG_A(0, 0, 3); STG_B(0, 0, 1);
  STG_A(1, 1, 0); STG_A(1, 1, 1); STG_B(1, 1, 0); STG_A(1, 1, 2); STG_A(1, 1, 3); STG_B(1, 1, 1);

  int q = 0;
  for (int t = 0; t < 32; ++t) {
    if (t < 31) {
      asm volatile("s_waitcnt vmcnt(6)" ::: "memory");
    } else {
      asm volatile("s_waitcnt vmcnt(0)" ::: "memory");
    }
    __builtin_amdgcn_s_barrier();
    __builtin_amdgcn_sched_barrier(0);
    const char* Aq = (const char*)lds + q * 49152;
    const int q2 = (q == 0) ? 2 : q - 1;

    // ---- phase A: read B(kk0,kk1) + A-half0; 3 stages; 16 MFMA ----
    bf16x8 b0[4], b1[4], a0[2], a1[2];
#pragma unroll
    for (int n = 0; n < 4; ++n) b0[n] = *(const bf16x8*)(Aq + bRow + n * 2048 + x0);
#pragma unroll
    for (int n = 0; n < 4; ++n) b1[n] = *(const bf16x8*)(Aq + bRow + n * 2048 + x1);
#pragma unroll
    for (int m = 0; m < 2; ++m) a0[m] = *(const bf16x8*)(Aq + aRow + m * 2048 + x0);
#pragma unroll
    for (int m = 0; m < 2; ++m) a1[m] = *(const bf16x8*)(Aq + aRow + m * 2048 + x1);
    if (t < 30) { STG_A(q2, t + 2, 0); STG_A(q2, t + 2, 1); STG_B(q2, t + 2, 0); }
    __builtin_amdgcn_sched_barrier(0);
    __builtin_amdgcn_s_setprio(1);
#pragma unroll
    for (int m = 0; m < 2; ++m)
#pragma unroll
      for (int n = 0; n < 4; ++n) acc[m][n] = MFMA16(a0[m], b0[n], acc[m][n]);
#pragma unroll
    for (int m = 0; m < 2; ++m)
#pragma unroll
      for (int n = 0; n < 4; ++n) acc[m][n] = MFMA16(a1[m], b1[n], acc[m][n]);
    __builtin_amdgcn_s_setprio(0);

    // ---- phase B: read A-half1 (during phase-A MFMA drain); 3 stages; barrier; 16 MFMA ----
    bf16x8 c0[2], c1[2];
#pragma unroll
    for (int m = 0; m < 2; ++m) c0[m] = *(const bf16x8*)(Aq + aRow + (m + 2) * 2048 + x0);
#pragma unroll
    for (int m = 0; m < 2; ++m) c1[m] = *(const bf16x8*)(Aq + aRow + (m + 2) * 2048 + x1);
    if (t < 30) { STG_A(q2, t + 2, 2); STG_A(q2, t + 2, 3); STG_B(q2, t + 2, 1); }
    __builtin_amdgcn_sched_barrier(0);
    __builtin_amdgcn_s_barrier();       // read-latency cover; keeps waves phase-locked
    __builtin_amdgcn_sched_barrier(0);
    __builtin_amdgcn_s_setprio(1);
#pragma unroll
    for (int m = 0; m < 2; ++m)
#pragma unroll
      for (int n = 0; n < 4; ++n) acc[m + 2][n] = MFMA16(c0[m], b0[n], acc[m + 2][n]);
#pragma unroll
    for (int m = 0; m < 2; ++m)
#pragma unroll
      for (int n = 0; n < 4; ++n) acc[m + 2][n] = MFMA16(c1[m], b1[n], acc[m + 2][n]);
    __builtin_amdgcn_s_setprio(0);
    q = (q == 2) ? 0 : q + 1;
  }
#undef STG_A
#undef STG_B

  // ---- epilogue ----
  if constexpr (MODE == 2) {
    const int sect = bn >> 11;  // 0=Q, 1=K, 2=V (buffers 16MB apart)
    u16* Cq = (u16*)Cv + (size_t)sect * 8388608;
    const int cb = (bn & 2047) + wc * 64;
    if (sect < 2) {
      const float qsc = (sect == 0) ? 0.08838834764831845f : 1.0f;
      float freq[4];
#pragma unroll
      for (int n = 0; n < 4; ++n) {
        const int c = cb + n * 16 + lo16;
        freq[n] = exp2f((float)((c & 127) >> 1) * -0.2076205059304601f);
      }
      const float sg = (lo16 & 1) ? 1.f : -1.f;
#pragma unroll
      for (int m = 0; m < 4; ++m) {
        const int row = bm + wr * 64 + m * 16 + hi * 4;
#pragma unroll
        for (int r = 0; r < 4; ++r) {
          const float p = (float)pos[row + r];
#pragma unroll
          for (int n = 0; n < 4; ++n) {
            const float ang = p * freq[n];
            const float sn = __sinf(ang);
            const float cs = __cosf(ang);
            const float v = acc[m][n][r];
            const float pv = __shfl_xor(v, 1);
            Cq[(size_t)(row + r) * 2048 + cb + n * 16 + lo16] =
                f2bf((v * cs + sg * pv * sn) * qsc);
          }
        }
      }
    } else {
      // V section: LDS-transpose, write VT [B,H,dk,S] directly
      __syncthreads();
#pragma unroll
      for (int m = 0; m < 4; ++m) {
#pragma unroll
        for (int n = 0; n < 4; ++n) {
          const int d = wc * 64 + n * 16 + lo16;
          const int tokb = wr * 64 + m * 16 + hi * 4;
#pragma unroll
          for (int r = 0; r < 4; ++r)
            lds[d * 260 + tokb + r] = f2bf(acc[m][n][r]);
        }
      }
      __syncthreads();
      const int b = bm >> 11, hh = (bn & 2047) >> 7;
      u16* vt = Cq + ((size_t)((b * 16 + hh) * 128)) * 2048 + (bm & 2047);
#pragma unroll
      for (int j = 0; j < 4; ++j) {
        const int d = (tid >> 4) + j * 32;
        const int t0 = (tid & 15) * 16;
        const u16* src = lds + d * 260 + t0;
        u16* dst = vt + (size_t)d * 2048 + t0;
#pragma unroll
        for (int w = 0; w < 4; ++w)
          *(u16x4*)(dst + w * 4) = *(const u16x4*)(src + w * 4);
      }
    }
  } else {
    float* C = (float*)Cv;
    const int cb = bn + wc * 64;
#pragma unroll
    for (int m = 0; m < 4; ++m)
#pragma unroll
      for (int n = 0; n < 4; ++n)
#pragma unroll
        for (int r = 0; r < 4; ++r)
          C[(size_t)(bm + wr * 64 + m * 16 + hi * 4 + r) * 2048 + cb + n * 16 + lo16] =
              acc[m][n][r];
  }
}

// ------------- causal flash attention v7 (unchanged from round 12) -------------
__global__ __launch_bounds__(256, 2) void flash_attn4(const u16* __restrict__ Qb,
                                                      const u16* __restrict__ Kb,
                                                      const u16* __restrict__ VT,
                                                      u16* __restrict__ Ob) {
  constexpr int S = 2048, HD = 2048;
  const int g = (int)blockIdx.x;
  const int xcd = g & 7, slot = g >> 3;
  const int bh = xcd * 4 + (slot & 3);
  const int pairid = slot >> 2;
  const int b = bh >> 4, h = bh & 15;
  const int tid = threadIdx.x, lane = tid & 63, wid = tid >> 6;

  __shared__ u16 Ks[2][64 * 128];
  __shared__ u16 Vs[2][128 * 64];
  __shared__ u16 Ps[4][16 * 64];

  const size_t base = (size_t)b * S * HD + (size_t)h * 128;
  const u16* Qp = Qb + base;
  const u16* Kp = Kb + base;
  const u16* VTp = VT + (size_t)bh * 128 * S;
  u16* Op = Ob + base;

  const f32x4 z4 = {0.f, 0.f, 0.f, 0.f};
  const int kKv = (lane >> 4);
  const int kC16 = (lane & 15);
  const int vD = (lane >> 3);
  const int vC16 = (lane & 7);

#define STAGE(pb, kv0_)                                                                   \
  {                                                                                       \
    _Pragma("unroll") for (int c = 0; c < 4; ++c) {                                       \
      const int ch = wid * 4 + c;                                                         \
      {                                                                                   \
        const int kv = ch * 4 + kKv;                                                      \
        const int c16 = kC16 ^ (kv & 7);                                                  \
        gload16(Kp + (size_t)((kv0_) + kv) * HD + c16 * 8, (char*)Ks[pb] + ch * 1024);    \
      }                                                                                   \
      {                                                                                   \
        const int d = ch * 8 + vD;                                                        \
        const int c16 = vC16 ^ (d & 7);                                                   \
        gload16(VTp + (size_t)d * S + (kv0_) + c16 * 8, (char*)Vs[pb] + ch * 1024);       \
      }                                                                                   \
    }                                                                                     \
  }

#pragma unroll
  for (int half = 0; half < 2; ++half) {
    const int qt = half ? pairid : 31 - pairid;
    const int q0 = qt * 64;

    bf16x8 qf[4];
    {
      const int qr = q0 + wid * 16 + (lane & 15);
      const int kc = (lane >> 4) * 8;
#pragma unroll
      for (int kb = 0; kb < 4; ++kb)
        qf[kb] = *(const bf16x8*)(Qp + (size_t)qr * HD + kb * 32 + kc);
    }

    f32x4 accO[8];
#pragma unroll
    for (int d = 0; d < 8; ++d) accO[d] = z4;
    float m_r[4] = {-INFINITY, -INFINITY, -INFINITY, -INFINITY};
    float l_r[4] = {0.f, 0.f, 0.f, 0.f};

    STAGE(0, 0);

    for (int t = 0; t <= qt; ++t) {
      const int cur = t & 1;
      const int kv0 = t * 64;
      if (t < qt) {
        STAGE(cur ^ 1, kv0 + 64);
        asm volatile("s_waitcnt vmcnt(8)" ::: "memory");
      } else {
        asm volatile("s_waitcnt vmcnt(0)" ::: "memory");
      }
      __builtin_amdgcn_s_barrier();
      __builtin_amdgcn_sched_barrier(0);

      const u16* Ksc = Ks[cur];
      const u16* Vsc = Vs[cur];
      f32x4 accS[4];
#pragma unroll
      for (int nb = 0; nb < 4; ++nb) accS[nb] = z4;

      __builtin_amdgcn_s_setprio(1);
#pragma unroll
      for (int nb = 0; nb < 4; ++nb) {
        const int kv = nb * 16 + (lane & 15);
#pragma unroll
        for (int kb = 0; kb < 4; ++kb) {
          const int c16 = (kb * 4 + (lane >> 4)) ^ (kv & 7);
          bf16x8 kf = *(const bf16x8*)((char*)Ksc + kv * 256 + c16 * 16);
          accS[nb] = MFMA16(qf[kb], kf, accS[nb]);
        }
      }
      __builtin_amdgcn_s_setprio(0);

      if (t == qt) {
#pragma unroll
        for (int nb = 0; nb < 4; ++nb) {
          const int kv = kv0 + nb * 16 + (lane & 15);
          const int qrow = q0 + wid * 16 + (lane >> 4) * 4;
#pragma unroll
          for (int j = 0; j < 4; ++j)
            if (kv > qrow + j) accS[nb][j] = -INFINITY;
        }
      }

      float lm[4];
#pragma unroll
      for (int j = 0; j < 4; ++j)
        lm[j] = fmaxf(fmaxf(accS[0][j], accS[1][j]), fmaxf(accS[2][j], accS[3][j]));
      const bool ok = (lm[0] <= m_r[0] + 8.f) && (lm[1] <= m_r[1] + 8.f) &&
                      (lm[2] <= m_r[2] + 8.f) && (lm[3] <= m_r[3] + 8.f);
      if (!__all(ok)) {
#pragma unroll
        for (int j = 0; j < 4; ++j) {
          float mx = lm[j];
#pragma unroll
          for (int off = 1; off < 16; off <<= 1) mx = fmaxf(mx, __shfl_xor(mx, off));
          const float mn = fmaxf(m_r[j], mx);
          const float sc = __expf(m_r[j] - mn);
          m_r[j] = mn;
          l_r[j] *= sc;
#pragma unroll
          for (int db = 0; db < 8; ++db) accO[db][j] *= sc;
        }
      }

      u16* Pw = &Ps[wid][0];
#pragma unroll
      for (int j = 0; j < 4; ++j) {
        float s = 0.f;
#pragma unroll
        for (int nb = 0; nb < 4; ++nb) {
          const float p = __expf(accS[nb][j] - m_r[j]);
          accS[nb][j] = p;
          s += p;
        }
        l_r[j] += s;
        const int ql = (lane >> 4) * 4 + j;
#pragma unroll
        for (int nb = 0; nb < 4; ++nb) {
          const int col = nb * 16 + (lane & 15);
          const int byteoff = ql * 128 + ((((col >> 3) ^ (ql & 7))) << 4) + (col & 7) * 2;
          *(u16*)((char*)Pw + byteoff) = f2bf(accS[nb][j]);
        }
      }

#pragma unroll
      for (int kb2 = 0; kb2 < 2; ++kb2) {
        const int ql = lane & 15;
        const int c16a = (kb2 * 4 + (lane >> 4)) ^ (ql & 7);
        bf16x8 pa = *(const bf16x8*)((char*)Pw + ql * 128 + c16a * 16);
        __builtin_amdgcn_s_setprio(1);
#pragma unroll
        for (int db = 0; db < 8; ++db) {
          const int d = db * 16 + (lane & 15);
          const int c16 = (kb2 * 4 + (lane >> 4)) ^ (d & 7);
          bf16x8 vf = *(const bf16x8*)((char*)Vsc + d * 128 + c16 * 16);
          accO[db] = MFMA16(pa, vf, accO[db]);
        }
        __builtin_amdgcn_s_setprio(0);
      }
      __builtin_amdgcn_sched_barrier(0);
      __builtin_amdgcn_s_barrier();
    }

    float inv[4];
#pragma unroll
    for (int j = 0; j < 4; ++j) {
      float l = l_r[j];
#pragma unroll
      for (int off = 1; off < 16; off <<= 1) l += __shfl_xor(l, off);
      inv[j] = 1.f / l;
    }
#pragma unroll
    for (int db = 0; db < 8; ++db)
#pragma unroll
      for (int j = 0; j < 4; ++j) {
        const int row = q0 + wid * 16 + (lane >> 4) * 4 + j;
        Op[(size_t)row * HD + db * 16 + (lane & 15)] = f2bf(accO[db][j] * inv[j]);
      }
  }
#undef STAGE
}

extern "C" void kernel_launch(void* const* d_in, const int* in_sizes, int n_in,
                              void* d_out, int out_size, void* d_ws, size_t ws_size,
                              hipStream_t stream) {
  const float* x  = (const float*)d_in[0];
  const int*   tp = (const int*)d_in[1];
  const float* WQ = (const float*)d_in[2];
  const float* WK = (const float*)d_in[3];
  const float* WV = (const float*)d_in[4];
  const float* WO = (const float*)d_in[5];

  const size_t MB = 1024 * 1024;
  if (ws_size < 112 * MB) return;
  char* ws = (char*)d_ws;
  u16* xb  = (u16*)(ws + 0 * MB);
  u16* wqt = (u16*)(ws + 16 * MB);   // wqt/wkt/wvt/wot contiguous, 8MB each
  u16* wot = (u16*)(ws + 40 * MB);
  u16* Qb  = (u16*)(ws + 48 * MB);   // Q(48MB) K(64MB) VT(80MB) -- gemm8<2> sect offsets
  u16* Kb  = (u16*)(ws + 64 * MB);
  u16* VTb = (u16*)(ws + 80 * MB);
  u16* Obf = (u16*)(ws + 96 * MB);

  {
    dim3 g(64, 64, 6), blk(32, 8);
    prep<<<g, blk, 0, stream>>>(x, WQ, WK, WV, WO, xb, wqt);
  }
  // fused QKV projection + RoPE + V-transpose: -> Qb | Kb | VTb
  gemm8<2><<<768, 512, 0, stream>>>(xb, wqt, (void*)Qb, tp, 48);

  flash_attn4<<<512, 256, 0, stream>>>(Qb, Kb, VTb, Obf);

  // output projection -> f32 d_out
  gemm8<1><<<256, 512, 0, stream>>>(Obf, wot, d_out, nullptr, 16);
}

// Round 14
// 236.137 us; speedup vs baseline: 1.2235x; 1.0013x over previous
//
#include <hip/hip_runtime.h>
#include <hip/hip_bf16.h>
#include <cstdint>
#include <cstddef>

typedef unsigned short u16;
typedef __attribute__((ext_vector_type(4))) unsigned short u16x4;
typedef __attribute__((ext_vector_type(8))) unsigned short u16x8;
typedef __attribute__((ext_vector_type(8))) __bf16 bf16x8;
typedef __attribute__((ext_vector_type(4))) float f32x4;

#define MFMA16(a, b, c) __builtin_amdgcn_mfma_f32_16x16x32_bf16((a), (b), (c), 0, 0, 0)

__device__ __forceinline__ u16 f2bf(float f) {
  uint32_t u = __builtin_bit_cast(uint32_t, f);
  u += 0x7FFFu + ((u >> 16) & 1u);
  return (u16)(u >> 16);
}
__device__ __forceinline__ float bf2f(u16 h) {
  return __builtin_bit_cast(float, (uint32_t)h << 16);
}

typedef const __attribute__((address_space(1))) void gv_t;
typedef __attribute__((address_space(3))) void lv_t;
__device__ __forceinline__ void gload16(const void* g, void* l) {
  __builtin_amdgcn_global_load_lds((gv_t*)g, (lv_t*)l, 16, 0, 0);
}

// ------- prep: z=0..3 -> transpose+cvt W[z]; z=4..5 -> x f32->bf16 (merged launch) -------
__global__ void prep(const float* __restrict__ x, const float* __restrict__ w0,
                     const float* __restrict__ w1, const float* __restrict__ w2,
                     const float* __restrict__ w3, u16* __restrict__ xb,
                     u16* __restrict__ wtbase) {
  const int z = blockIdx.z;
  const int bx = blockIdx.x, by = blockIdx.y;
  const int tx = threadIdx.x, ty = threadIdx.y;
  if (z >= 4) {
    const int i = ((z - 4) * 4096 + by * 64 + bx) * 256 + ty * 32 + tx;
    float4 v = ((const float4*)x)[i];
    u16x4 o;
    o[0] = f2bf(v.x); o[1] = f2bf(v.y); o[2] = f2bf(v.z); o[3] = f2bf(v.w);
    ((u16x4*)xb)[i] = o;
    return;
  }
  __shared__ float tile[32][33];
  const float* in = (z == 0) ? w0 : (z == 1) ? w1 : (z == 2) ? w2 : w3;
  u16* out = wtbase + (size_t)z * 4194304;
#pragma unroll
  for (int i = 0; i < 32; i += 8)
    tile[ty + i][tx] = in[(size_t)(by * 32 + ty + i) * 2048 + bx * 32 + tx];
  __syncthreads();
#pragma unroll
  for (int i = 0; i < 32; i += 8)
    out[(size_t)(bx * 32 + ty + i) * 2048 + by * 32 + tx] = f2bf(tile[tx][ty + i]);
}

// ============ phase-split GEMM (unchanged from round 13) ============
template <int MODE>
__global__ __launch_bounds__(512, 1) void gemm8(const u16* __restrict__ A,
                                                const u16* __restrict__ Bt,
                                                void* __restrict__ Cv,
                                                const int* __restrict__ pos, int nbn) {
  constexpr int K = 2048;
  __shared__ __align__(16) u16 lds[73728];  // 3 x (A 32KB + B 16KB) = 144KB
  const int tid = threadIdx.x, lane = tid & 63;
  const int lo16 = lane & 15, hi = lane >> 4;
  const int wid = tid >> 6;
  const int wr = wid >> 1, wc = wid & 1;

  const int xcd = (int)blockIdx.x & 7;
  const int idx = (int)blockIdx.x >> 3;
  const int cpx = nbn >> 3;
  const int bn = (xcd * cpx + idx % cpx) * 128;
  const int bm = (idx / cpx) * 256;

  const int srow = tid >> 3;
  const int scol = ((tid & 7) ^ (srow & 7)) * 8;
  const u16* Arow = A + (size_t)(bm + srow) * K + scol;
  const u16* Brow = Bt + (size_t)(bn + srow) * K + scol;
  char* dstbase = (char*)lds + tid * 16;

#define STG_A(qb_, t_, r_) \
  gload16(Arow + (size_t)(r_) * 64 * K + (t_) * 64, dstbase + (qb_) * 49152 + (r_) * 8192)
#define STG_B(qb_, t_, r_) \
  gload16(Brow + (size_t)(r_) * 64 * K + (t_) * 64, dstbase + (qb_) * 49152 + 32768 + (r_) * 8192)

  f32x4 acc[4][4];
  const f32x4 z4 = {0.f, 0.f, 0.f, 0.f};
#pragma unroll
  for (int m = 0; m < 4; ++m)
#pragma unroll
    for (int n = 0; n < 4; ++n) acc[m][n] = z4;

  const int xork = lo16 & 7;
  const int aRow = (wr * 64 + lo16) * 128;
  const int bRow = 32768 + (wc * 64 + lo16) * 128;
  const int x0 = ((hi ^ xork)) << 4;
  const int x1 = (((4 + hi) ^ xork)) << 4;

  STG_A(0, 0, 0); STG_A(0, 0, 1); STG_B(0, 0, 0); STG_A(0, 0, 2); STG_A(0, 0, 3); STG_B(0, 0, 1);
  STG_A(1, 1, 0); STG_A(1, 1, 1); STG_B(1, 1, 0); STG_A(1, 1, 2); STG_A(1, 1, 3); STG_B(1, 1, 1);

  int q = 0;
  for (int t = 0; t < 32; ++t) {
    if (t < 31) {
      asm volatile("s_waitcnt vmcnt(6)" ::: "memory");
    } else {
      asm volatile("s_waitcnt vmcnt(0)" ::: "memory");
    }
    __builtin_amdgcn_s_barrier();
    __builtin_amdgcn_sched_barrier(0);
    const char* Aq = (const char*)lds + q * 49152;
    const int q2 = (q == 0) ? 2 : q - 1;

    bf16x8 b0[4], b1[4], a0[2], a1[2];
#pragma unroll
    for (int n = 0; n < 4; ++n) b0[n] = *(const bf16x8*)(Aq + bRow + n * 2048 + x0);
#pragma unroll
    for (int n = 0; n < 4; ++n) b1[n] = *(const bf16x8*)(Aq + bRow + n * 2048 + x1);
#pragma unroll
    for (int m = 0; m < 2; ++m) a0[m] = *(const bf16x8*)(Aq + aRow + m * 2048 + x0);
#pragma unroll
    for (int m = 0; m < 2; ++m) a1[m] = *(const bf16x8*)(Aq + aRow + m * 2048 + x1);
    if (t < 30) { STG_A(q2, t + 2, 0); STG_A(q2, t + 2, 1); STG_B(q2, t + 2, 0); }
    __builtin_amdgcn_sched_barrier(0);
    __builtin_amdgcn_s_setprio(1);
#pragma unroll
    for (int m = 0; m < 2; ++m)
#pragma unroll
      for (int n = 0; n < 4; ++n) acc[m][n] = MFMA16(a0[m], b0[n], acc[m][n]);
#pragma unroll
    for (int m = 0; m < 2; ++m)
#pragma unroll
      for (int n = 0; n < 4; ++n) acc[m][n] = MFMA16(a1[m], b1[n], acc[m][n]);
    __builtin_amdgcn_s_setprio(0);

    bf16x8 c0[2], c1[2];
#pragma unroll
    for (int m = 0; m < 2; ++m) c0[m] = *(const bf16x8*)(Aq + aRow + (m + 2) * 2048 + x0);
#pragma unroll
    for (int m = 0; m < 2; ++m) c1[m] = *(const bf16x8*)(Aq + aRow + (m + 2) * 2048 + x1);
    if (t < 30) { STG_A(q2, t + 2, 2); STG_A(q2, t + 2, 3); STG_B(q2, t + 2, 1); }
    __builtin_amdgcn_sched_barrier(0);
    __builtin_amdgcn_s_barrier();
    __builtin_amdgcn_sched_barrier(0);
    __builtin_amdgcn_s_setprio(1);
#pragma unroll
    for (int m = 0; m < 2; ++m)
#pragma unroll
      for (int n = 0; n < 4; ++n) acc[m + 2][n] = MFMA16(c0[m], b0[n], acc[m + 2][n]);
#pragma unroll
    for (int m = 0; m < 2; ++m)
#pragma unroll
      for (int n = 0; n < 4; ++n) acc[m + 2][n] = MFMA16(c1[m], b1[n], acc[m + 2][n]);
    __builtin_amdgcn_s_setprio(0);
    q = (q == 2) ? 0 : q + 1;
  }
#undef STG_A
#undef STG_B

  if constexpr (MODE == 2) {
    const int sect = bn >> 11;
    u16* Cq = (u16*)Cv + (size_t)sect * 8388608;
    const int cb = (bn & 2047) + wc * 64;
    if (sect < 2) {
      const float qsc = (sect == 0) ? 0.08838834764831845f : 1.0f;
      float freq[4];
#pragma unroll
      for (int n = 0; n < 4; ++n) {
        const int c = cb + n * 16 + lo16;
        freq[n] = exp2f((float)((c & 127) >> 1) * -0.2076205059304601f);
      }
      const float sg = (lo16 & 1) ? 1.f : -1.f;
#pragma unroll
      for (int m = 0; m < 4; ++m) {
        const int row = bm + wr * 64 + m * 16 + hi * 4;
#pragma unroll
        for (int r = 0; r < 4; ++r) {
          const float p = (float)pos[row + r];
#pragma unroll
          for (int n = 0; n < 4; ++n) {
            const float ang = p * freq[n];
            const float sn = __sinf(ang);
            const float cs = __cosf(ang);
            const float v = acc[m][n][r];
            const float pv = __shfl_xor(v, 1);
            Cq[(size_t)(row + r) * 2048 + cb + n * 16 + lo16] =
                f2bf((v * cs + sg * pv * sn) * qsc);
          }
        }
      }
    } else {
      __syncthreads();
#pragma unroll
      for (int m = 0; m < 4; ++m) {
#pragma unroll
        for (int n = 0; n < 4; ++n) {
          const int d = wc * 64 + n * 16 + lo16;
          const int tokb = wr * 64 + m * 16 + hi * 4;
#pragma unroll
          for (int r = 0; r < 4; ++r)
            lds[d * 260 + tokb + r] = f2bf(acc[m][n][r]);
        }
      }
      __syncthreads();
      const int b = bm >> 11, hh = (bn & 2047) >> 7;
      u16* vt = Cq + ((size_t)((b * 16 + hh) * 128)) * 2048 + (bm & 2047);
#pragma unroll
      for (int j = 0; j < 4; ++j) {
        const int d = (tid >> 4) + j * 32;
        const int t0 = (tid & 15) * 16;
        const u16* src = lds + d * 260 + t0;
        u16* dst = vt + (size_t)d * 2048 + t0;
#pragma unroll
        for (int w = 0; w < 4; ++w)
          *(u16x4*)(dst + w * 4) = *(const u16x4*)(src + w * 4);
      }
    }
  } else {
    float* C = (float*)Cv;
    const int cb = bn + wc * 64;
#pragma unroll
    for (int m = 0; m < 4; ++m)
#pragma unroll
      for (int n = 0; n < 4; ++n)
#pragma unroll
        for (int r = 0; r < 4; ++r)
          C[(size_t)(bm + wr * 64 + m * 16 + hi * 4 + r) * 2048 + cb + n * 16 + lo16] =
              acc[m][n][r];
  }
}

// ---- per-tile step body for the merged flash loop (inlined; all indices static) ----
__device__ __forceinline__ void attn_step(const char* Ksc, const char* Vsc, char* Pw,
                                          const bf16x8* qf, f32x4* accO,
                                          float* m_r, float* l_r,
                                          bool diag, int kv0, int qrow0, int lane) {
  const f32x4 z4 = {0.f, 0.f, 0.f, 0.f};
  f32x4 accS[4];
#pragma unroll
  for (int nb = 0; nb < 4; ++nb) accS[nb] = z4;

  // ---- S = Q K^T ----
  __builtin_amdgcn_s_setprio(1);
#pragma unroll
  for (int nb = 0; nb < 4; ++nb) {
    const int kv = nb * 16 + (lane & 15);
#pragma unroll
    for (int kb = 0; kb < 4; ++kb) {
      const int c16 = (kb * 4 + (lane >> 4)) ^ (kv & 7);
      bf16x8 kf = *(const bf16x8*)(Ksc + kv * 256 + c16 * 16);
      accS[nb] = MFMA16(qf[kb], kf, accS[nb]);
    }
  }
  __builtin_amdgcn_s_setprio(0);

  // ---- causal mask (diagonal step only) ----
  if (diag) {
#pragma unroll
    for (int nb = 0; nb < 4; ++nb) {
      const int kv = kv0 + nb * 16 + (lane & 15);
#pragma unroll
      for (int j = 0; j < 4; ++j)
        if (kv > qrow0 + j) accS[nb][j] = -INFINITY;
    }
  }

  // ---- defer-max (T13, THR=8) ----
  float lm[4];
#pragma unroll
  for (int j = 0; j < 4; ++j)
    lm[j] = fmaxf(fmaxf(accS[0][j], accS[1][j]), fmaxf(accS[2][j], accS[3][j]));
  const bool ok = (lm[0] <= m_r[0] + 8.f) && (lm[1] <= m_r[1] + 8.f) &&
                  (lm[2] <= m_r[2] + 8.f) && (lm[3] <= m_r[3] + 8.f);
  if (!__all(ok)) {
#pragma unroll
    for (int j = 0; j < 4; ++j) {
      float mx = lm[j];
#pragma unroll
      for (int off = 1; off < 16; off <<= 1) mx = fmaxf(mx, __shfl_xor(mx, off));
      const float mn = fmaxf(m_r[j], mx);
      const float sc = __expf(m_r[j] - mn);
      m_r[j] = mn;
      l_r[j] *= sc;
#pragma unroll
      for (int db = 0; db < 8; ++db) accO[db][j] *= sc;
    }
  }

  // ---- exponentiate, per-lane partial sum, P write ----
#pragma unroll
  for (int j = 0; j < 4; ++j) {
    float s = 0.f;
#pragma unroll
    for (int nb = 0; nb < 4; ++nb) {
      const float p = __expf(accS[nb][j] - m_r[j]);
      accS[nb][j] = p;
      s += p;
    }
    l_r[j] += s;
    const int ql = (lane >> 4) * 4 + j;
#pragma unroll
    for (int nb = 0; nb < 4; ++nb) {
      const int col = nb * 16 + (lane & 15);
      const int byteoff = ql * 128 + ((((col >> 3) ^ (ql & 7))) << 4) + (col & 7) * 2;
      *(u16*)(Pw + byteoff) = f2bf(accS[nb][j]);
    }
  }

  // ---- O += P V ----
#pragma unroll
  for (int kb2 = 0; kb2 < 2; ++kb2) {
    const int ql = lane & 15;
    const int c16a = (kb2 * 4 + (lane >> 4)) ^ (ql & 7);
    bf16x8 pa = *(const bf16x8*)(Pw + ql * 128 + c16a * 16);
    __builtin_amdgcn_s_setprio(1);
#pragma unroll
    for (int db = 0; db < 8; ++db) {
      const int d = db * 16 + (lane & 15);
      const int c16 = (kb2 * 4 + (lane >> 4)) ^ (d & 7);
      bf16x8 vf = *(const bf16x8*)(Vsc + d * 128 + c16 * 16);
      accO[db] = MFMA16(pa, vf, accO[db]);
    }
    __builtin_amdgcn_s_setprio(0);
  }
}

// ------------- causal flash attention v8: MERGED complementary pair -------------
// One kv-loop per block covering tile A (qtA=31-p) and tile B (qtB=p); B's KV range
// is a subset of A's, so K/V are staged ONCE (avg steps 34 -> 32-p, compute-equiv
// uniform at 33). Double-buffered, counted vmcnt, defer-max, per-lane l.
__global__ __launch_bounds__(256, 2) void flash_attn8(const u16* __restrict__ Qb,
                                                      const u16* __restrict__ Kb,
                                                      const u16* __restrict__ VT,
                                                      u16* __restrict__ Ob) {
  constexpr int S = 2048, HD = 2048;
  const int g = (int)blockIdx.x;
  const int xcd = g & 7, slot = g >> 3;      // 64 slots per XCD
  const int bh = xcd * 4 + (slot & 3);       // 4 heads per XCD
  const int pairid = slot >> 2;              // 0..15 (heavy pairs dispatch first)
  const int b = bh >> 4, h = bh & 15;
  const int tid = threadIdx.x, lane = tid & 63, wid = tid >> 6;
  const int qtA = 31 - pairid, qtB = pairid;
  const int q0a = qtA * 64, q0b = qtB * 64;

  __shared__ u16 Ks[2][64 * 128];
  __shared__ u16 Vs[2][128 * 64];
  __shared__ u16 Ps[4][16 * 64];

  const size_t base = (size_t)b * S * HD + (size_t)h * 128;
  const u16* Qp = Qb + base;
  const u16* Kp = Kb + base;
  const u16* VTp = VT + (size_t)bh * 128 * S;
  u16* Op = Ob + base;

  const f32x4 z4 = {0.f, 0.f, 0.f, 0.f};
  const int kKv = (lane >> 4);
  const int kC16 = (lane & 15);
  const int vD = (lane >> 3);
  const int vC16 = (lane & 7);

#define STAGE(pb, kv0_)                                                                   \
  {                                                                                       \
    _Pragma("unroll") for (int c = 0; c < 4; ++c) {                                       \
      const int ch = wid * 4 + c;                                                         \
      {                                                                                   \
        const int kv = ch * 4 + kKv;                                                      \
        const int c16 = kC16 ^ (kv & 7);                                                  \
        gload16(Kp + (size_t)((kv0_) + kv) * HD + c16 * 8, (char*)Ks[pb] + ch * 1024);    \
      }                                                                                   \
      {                                                                                   \
        const int d = ch * 8 + vD;                                                        \
        const int c16 = vC16 ^ (d & 7);                                                   \
        gload16(VTp + (size_t)d * S + (kv0_) + c16 * 8, (char*)Vs[pb] + ch * 1024);       \
      }                                                                                   \
    }                                                                                     \
  }

  // Q fragments for both tiles
  bf16x8 qfA[4], qfB[4];
  {
    const int kc = (lane >> 4) * 8;
    const int qrA = q0a + wid * 16 + (lane & 15);
    const int qrB = q0b + wid * 16 + (lane & 15);
#pragma unroll
    for (int kb = 0; kb < 4; ++kb) {
      qfA[kb] = *(const bf16x8*)(Qp + (size_t)qrA * HD + kb * 32 + kc);
      qfB[kb] = *(const bf16x8*)(Qp + (size_t)qrB * HD + kb * 32 + kc);
    }
  }

  f32x4 accOA[8], accOB[8];
#pragma unroll
  for (int d = 0; d < 8; ++d) { accOA[d] = z4; accOB[d] = z4; }
  float mA[4] = {-INFINITY, -INFINITY, -INFINITY, -INFINITY};
  float lA[4] = {0.f, 0.f, 0.f, 0.f};
  float mB[4] = {-INFINITY, -INFINITY, -INFINITY, -INFINITY};
  float lB[4] = {0.f, 0.f, 0.f, 0.f};

  const int qrow0A = q0a + wid * 16 + (lane >> 4) * 4;
  const int qrow0B = q0b + wid * 16 + (lane >> 4) * 4;
  char* Pw = (char*)&Ps[wid][0];

  STAGE(0, 0);  // 8 loads in flight

  for (int t = 0; t <= qtA; ++t) {
    const int cur = t & 1;
    const int kv0 = t * 64;
    if (t < qtA) {
      STAGE(cur ^ 1, kv0 + 64);                          // +8 loads (tile t+1)
      asm volatile("s_waitcnt vmcnt(8)" ::: "memory");   // wait tile t's 8 only
    } else {
      asm volatile("s_waitcnt vmcnt(0)" ::: "memory");
    }
    __builtin_amdgcn_s_barrier();       // all waves: tile t resident
    __builtin_amdgcn_sched_barrier(0);

    const char* Ksc = (const char*)Ks[cur];
    const char* Vsc = (const char*)Vs[cur];

    // ---- tile A (always active) ----
    attn_step(Ksc, Vsc, Pw, qfA, accOA, mA, lA, t == qtA, kv0, qrow0A, lane);

    // ---- tile B (active while kv within its causal range; block-uniform branch) ----
    if (t <= qtB)
      attn_step(Ksc, Vsc, Pw, qfB, accOB, mB, lB, t == qtB, kv0, qrow0B, lane);

    __builtin_amdgcn_sched_barrier(0);
    __builtin_amdgcn_s_barrier();  // all waves done reading buf[cur]; no drain
  }
#undef STAGE

  // ---- epilogue: reduce per-lane l, normalize, store (both tiles) ----
  float invA[4], invB[4];
#pragma unroll
  for (int j = 0; j < 4; ++j) {
    float la = lA[j], lb = lB[j];
#pragma unroll
    for (int off = 1; off < 16; off <<= 1) {
      la += __shfl_xor(la, off);
      lb += __shfl_xor(lb, off);
    }
    invA[j] = 1.f / la;
    invB[j] = 1.f / lb;
  }
#pragma unroll
  for (int db = 0; db < 8; ++db)
#pragma unroll
    for (int j = 0; j < 4; ++j) {
      const int rowA = qrow0A + j;
      const int rowB = qrow0B + j;
      Op[(size_t)rowA * HD + db * 16 + (lane & 15)] = f2bf(accOA[db][j] * invA[j]);
      Op[(size_t)rowB * HD + db * 16 + (lane & 15)] = f2bf(accOB[db][j] * invB[j]);
    }
}

extern "C" void kernel_launch(void* const* d_in, const int* in_sizes, int n_in,
                              void* d_out, int out_size, void* d_ws, size_t ws_size,
                              hipStream_t stream) {
  const float* x  = (const float*)d_in[0];
  const int*   tp = (const int*)d_in[1];
  const float* WQ = (const float*)d_in[2];
  const float* WK = (const float*)d_in[3];
  const float* WV = (const float*)d_in[4];
  const float* WO = (const float*)d_in[5];

  const size_t MB = 1024 * 1024;
  if (ws_size < 112 * MB) return;
  char* ws = (char*)d_ws;
  u16* xb  = (u16*)(ws + 0 * MB);
  u16* wqt = (u16*)(ws + 16 * MB);   // wqt/wkt/wvt/wot contiguous, 8MB each
  u16* wot = (u16*)(ws + 40 * MB);
  u16* Qb  = (u16*)(ws + 48 * MB);   // Q(48MB) K(64MB) VT(80MB) -- gemm8<2> sect offsets
  u16* Kb  = (u16*)(ws + 64 * MB);
  u16* VTb = (u16*)(ws + 80 * MB);
  u16* Obf = (u16*)(ws + 96 * MB);

  {
    dim3 g(64, 64, 6), blk(32, 8);
    prep<<<g, blk, 0, stream>>>(x, WQ, WK, WV, WO, xb, wqt);
  }
  // fused QKV projection + RoPE + V-transpose: -> Qb | Kb | VTb
  gemm8<2><<<768, 512, 0, stream>>>(xb, wqt, (void*)Qb, tp, 48);

  flash_attn8<<<512, 256, 0, stream>>>(Qb, Kb, VTb, Obf);

  // output projection -> f32 d_out
  gemm8<1><<<256, 512, 0, stream>>>(Obf, wot, d_out, nullptr, 16);
}